// Round 21
// baseline (121.166 us; speedup 1.0000x reference)
//
#include <hip/hip_runtime.h>
#include <hip/hip_bf16.h>
#include <math.h>

// Problem constants
#define Bn  2
#define Tn  2048
#define Dn  1024
#define Hn  16
#define HDn 64
// M = B*T = 4096

typedef __attribute__((ext_vector_type(8))) short short8;
typedef __attribute__((ext_vector_type(8))) unsigned short u16x8;
typedef __attribute__((ext_vector_type(4))) unsigned short u16x4;
typedef __attribute__((ext_vector_type(4))) float f32x4;
typedef __attribute__((ext_vector_type(16))) float f32x16;
typedef unsigned short ushort_t;

#define MFMA16(a, b, c) __builtin_amdgcn_mfma_f32_16x16x32_bf16((a), (b), (c), 0, 0, 0)
#define MFMA32(a, b, c) __builtin_amdgcn_mfma_f32_32x32x16_bf16((a), (b), (c), 0, 0, 0)

__device__ __forceinline__ unsigned short f2b(float f) {
    union { float f; unsigned u; } v; v.f = f;
    unsigned r = (v.u + 0x7FFFu + ((v.u >> 16) & 1u)) >> 16;   // RNE
    return (unsigned short)r;
}
__device__ __forceinline__ void gload_lds16(const void* g, void* l) {
    __builtin_amdgcn_global_load_lds(
        (const __attribute__((address_space(1))) void*)g,
        (__attribute__((address_space(3))) void*)l, 16, 0, 0);
}
__device__ __forceinline__ unsigned cvt_pk(float lo, float hi) {
    unsigned r;
    asm("v_cvt_pk_bf16_f32 %0, %1, %2" : "=v"(r) : "v"(lo), "v"(hi));
    return r;
}
// permlane32_swap with DISTINCT SSA values only (b==a would coalesce registers).
// Inputs must come from compiler-scheduled code, never from an immediately-
// preceding hand-written asm op (R12 hazard lesson).
__device__ __forceinline__ void plswap(unsigned &a, unsigned &b) {
    asm volatile("v_permlane32_swap_b32 %0, %1" : "+v"(a), "+v"(b));
}
// cross-half (lane ^ 32) reductions via shfl — PROVEN form (R5-R19)
__device__ __forceinline__ float xhalf_max(float v) {
    return fmaxf(v, __shfl_xor(v, 32));
}
__device__ __forceinline__ float xhalf_add(float v) {
    return v + __shfl_xor(v, 32);
}
// bare 2^x (scores live in log2 domain; log2e folded into Q scale)
__device__ __forceinline__ float fexp2(float x) {
    float r;
    asm("v_exp_f32 %0, %1" : "=v"(r) : "v"(x));
    return r;
}
__device__ __forceinline__ float fmax3(float a, float b, float c) {
    float r;
    asm("v_max3_f32 %0, %1, %2, %3" : "=v"(r) : "v"(a), "v"(b), "v"(c));
    return r;
}

// ---------------------------------------------------------------------------
// Merged prep: blocks 0..2047 cast x (f32)->bf16 (vectorized);
// blocks 2048..6143 do both weight transposes (branch is block-uniform,
// so the transpose-path __syncthreads is safe).
// ---------------------------------------------------------------------------
__global__ __launch_bounds__(256) void prep_kernel(
    const float* __restrict__ x, ushort_t* __restrict__ xb,
    const float* __restrict__ Wq, ushort_t* __restrict__ Wqt,
    const float* __restrict__ Wp, ushort_t* __restrict__ Wpt)
{
    __shared__ float tile[32][33];
    const int bid = blockIdx.x;
    if (bid < 2048) {
        int i = bid * 256 + threadIdx.x;
        const float4* p = (const float4*)x;
        float4 a = p[i * 2], b = p[i * 2 + 1];
        u16x8 o;
        o[0] = f2b(a.x); o[1] = f2b(a.y); o[2] = f2b(a.z); o[3] = f2b(a.w);
        o[4] = f2b(b.x); o[5] = f2b(b.y); o[6] = f2b(b.z); o[7] = f2b(b.w);
        *(u16x8*)&xb[i * 8] = o;
        return;
    }
    const int idx = bid - 2048;               // 0..4095
    const int bx = idx & 127, ky = idx >> 7;  // 128 x-blocks, 32 k-blocks
    const float* W;
    ushort_t* Wt;
    int N, n0;
    if (bx < 96) { W = Wq; Wt = Wqt; N = 3072; n0 = bx * 32; }
    else         { W = Wp; Wt = Wpt; N = 1024; n0 = (bx - 96) * 32; }
    const int k0 = ky * 32;
    const int tx = threadIdx.x & 31, ty = threadIdx.x >> 5;
    #pragma unroll
    for (int i = 0; i < 4; ++i)
        tile[ty + i * 8][tx] = W[(size_t)(k0 + ty + i * 8) * N + n0 + tx];
    __syncthreads();
    #pragma unroll
    for (int i = 0; i < 4; ++i)
        Wt[(size_t)(n0 + ty + i * 8) * 1024 + k0 + tx] = f2b(tile[tx][ty + i * 8]);
}

// ---------------------------------------------------------------------------
// QKV GEMM, BM=64 x BN=128 (R19 proj64 occupancy trick applied to QKV):
// grid (24, 64) = 1536 blocks = 6/CU (was 768 = 3/CU -> latency-bound at
// MfmaUtil 21%). 4 waves = 2x2: wave owns 32 rows x 64 cols -> the 64-col
// wave slice is one head block, so the proven RoPE epilogue transfers
// verbatim. Same BK=32 + 2-phase prefetch + row-pair XOR swizzle + 2-D XCD
// chunking (bmc=16, bnc=12). LDS 24 KB/block.
// ---------------------------------------------------------------------------
__global__ __launch_bounds__(256) void gemm_qkv64_kernel(
    const ushort_t* __restrict__ A, const ushort_t* __restrict__ Bt,
    ushort_t* __restrict__ Qo, ushort_t* __restrict__ Ko, ushort_t* __restrict__ Vo)
{
    __shared__ __align__(16) ushort_t As[2][64 * 32];    // 4 KB each
    __shared__ __align__(16) ushort_t Bs[2][128 * 32];   // 8 KB each
    const int tid  = threadIdx.x;
    const int lane = tid & 63, wid = tid >> 6;
    const int l15 = lane & 15, lh = lane >> 4;
    const int wr = wid >> 1, wc = wid & 1;               // 2x2 waves

    // 2-D XCD chunk mapping: grid (24, 64); bmc = 16, bnc = 12
    const int nbx = gridDim.x;
    const int bid = blockIdx.y * nbx + blockIdx.x;
    const int xcd = bid & 7, r = bid >> 3;
    const int xm = xcd >> 1, xn = xcd & 1;               // 4 x 2 XCD regions
    const int bmc = gridDim.y >> 2;                      // 16
    const int bnc = nbx >> 1;                            // 12
    const int rm = r % bmc, rn = r / bmc;                // bm fast -> B reused
    const int bm = (xm * bmc + rm) * 64;
    const int bn = (xn * bnc + rn) * 128;

    f32x4 acc[2][4];
    #pragma unroll
    for (int i = 0; i < 2; ++i)
        #pragma unroll
        for (int j = 0; j < 4; ++j) acc[i][j] = (f32x4){0.f, 0.f, 0.f, 0.f};

    const ushort_t* Ag = A  + (size_t)bm * 1024;
    const ushort_t* Bg = Bt + (size_t)bn * 1024;

    auto STAGE = [&](int k0, int buf) {
        {   // A tile: 64 rows x 4 chunks = 256, 1 per thread
            int row = tid >> 2, kc = tid & 3;
            int src_k = k0 + ((kc ^ ((row >> 1) & 3)) * 8);
            gload_lds16(Ag + (size_t)row * 1024 + src_k, &As[buf][tid * 8]);
        }
        #pragma unroll
        for (int i = 0; i < 2; ++i) {   // B tile: 128 rows x 4 chunks = 512
            int idx = i * 256 + tid;
            int row = idx >> 2, kc = idx & 3;
            int src_k = k0 + ((kc ^ ((row >> 1) & 3)) * 8);
            gload_lds16(Bg + (size_t)row * 1024 + src_k, &Bs[buf][idx * 8]);
        }
    };

    STAGE(0, 0);
    __syncthreads();

    for (int t = 0; t < 32; ++t) {
        const int cur = t & 1;
        if (t + 1 < 32) STAGE((t + 1) * 32, cur ^ 1);

        short8 a[2], b[4];
        #pragma unroll
        for (int mi = 0; mi < 2; ++mi) {
            int ra = wr * 32 + mi * 16 + l15;
            a[mi] = *(const short8*)&As[cur][ra * 32 + ((lh ^ ((ra >> 1) & 3)) * 8)];
        }
        #pragma unroll
        for (int nj = 0; nj < 4; ++nj) {
            int rb = wc * 64 + nj * 16 + l15;
            b[nj] = *(const short8*)&Bs[cur][rb * 32 + ((lh ^ ((rb >> 1) & 3)) * 8)];
        }
        __builtin_amdgcn_s_setprio(1);
        #pragma unroll
        for (int mi = 0; mi < 2; ++mi)
            #pragma unroll
            for (int nj = 0; nj < 4; ++nj)
                acc[mi][nj] = MFMA16(a[mi], b[nj], acc[mi][nj]);
        __builtin_amdgcn_s_setprio(0);

        __syncthreads();
    }

    // epilogue: fused RoPE scatter (proven form; wave slice = one head block)
    const int n0 = bn + wc * 64;
    const int i3 = n0 >> 10;              // 0=q, 1=k, 2=v
    const int hh = (n0 >> 6) & 15;
    if (i3 == 2) {
        #pragma unroll
        for (int mi = 0; mi < 2; ++mi)
            #pragma unroll
            for (int r2 = 0; r2 < 4; ++r2) {
                int m = bm + wr * 32 + mi * 16 + lh * 4 + r2;
                int b_ = m >> 11, t = m & 2047;
                size_t ob = ((size_t)((b_ * Hn + hh) * Tn) + t) * HDn;
                #pragma unroll
                for (int nj = 0; nj < 4; ++nj)
                    Vo[ob + nj * 16 + l15] = f2b(acc[mi][nj][r2]);
            }
    } else {
        ushort_t* dst = i3 ? Ko : Qo;
        // q scale = 1/sqrt(HD) * log2(e)  -> scores in log2 domain
        const float sc = i3 ? 1.0f : 0.18033688f;
        const float inv0 = __powf(10000.0f, -(float)l15 * (1.0f / 32.0f));
        const float inv1 = __powf(10000.0f, -(float)(16 + l15) * (1.0f / 32.0f));
        #pragma unroll
        for (int mi = 0; mi < 2; ++mi)
            #pragma unroll
            for (int r2 = 0; r2 < 4; ++r2) {
                int m = bm + wr * 32 + mi * 16 + lh * 4 + r2;
                int b_ = m >> 11, t = m & 2047;
                size_t ob = ((size_t)((b_ * Hn + hh) * Tn) + t) * HDn;
                float tf = (float)t;
                #pragma unroll
                for (int nj = 0; nj < 2; ++nj) {
                    float fr = tf * (nj ? inv1 : inv0);
                    float cc, ss;
                    __sincosf(fr, &ss, &cc);
                    float v0 = acc[mi][nj][r2], v1 = acc[mi][nj + 2][r2];
                    int j = nj * 16 + l15;
                    dst[ob + j]      = f2b((v0 * cc - v1 * ss) * sc);
                    dst[ob + j + 32] = f2b((v1 * cc + v0 * ss) * sc);
                }
            }
    }
}

// ---------------------------------------------------------------------------
// Output projection GEMM, BM=64 x BN=128 (R19-proven): grid (8, 64) =
// 512 blocks = 2/CU. 4 waves = 1x4 column groups; acc[4][2].
// ---------------------------------------------------------------------------
__global__ __launch_bounds__(256) void gemm_proj64_kernel(
    const ushort_t* __restrict__ A, const ushort_t* __restrict__ Bt,
    float* __restrict__ C)
{
    __shared__ __align__(16) ushort_t As[2][64 * 32];
    __shared__ __align__(16) ushort_t Bs[2][128 * 32];
    const int tid  = threadIdx.x;
    const int lane = tid & 63, wid = tid >> 6;           // wid 0..3 = col group
    const int l15 = lane & 15, lh = lane >> 4;

    const int nbx = gridDim.x;
    const int bid = blockIdx.y * nbx + blockIdx.x;
    const int xcd = bid & 7, r = bid >> 3;
    const int xm = xcd >> 1, xn = xcd & 1;
    const int bmc = gridDim.y >> 2;
    const int bnc = nbx >> 1;
    const int rm = r % bmc, rn = r / bmc;
    const int bm = (xm * bmc + rm) * 64;
    const int bn = (xn * bnc + rn) * 128;

    f32x4 acc[4][2];
    #pragma unroll
    for (int i = 0; i < 4; ++i)
        #pragma unroll
        for (int j = 0; j < 2; ++j) acc[i][j] = (f32x4){0.f, 0.f, 0.f, 0.f};

    const ushort_t* Ag = A  + (size_t)bm * 1024;
    const ushort_t* Bg = Bt + (size_t)bn * 1024;

    auto STAGE = [&](int k0, int buf) {
        {
            int row = tid >> 2, kc = tid & 3;
            int src_k = k0 + ((kc ^ ((row >> 1) & 3)) * 8);
            gload_lds16(Ag + (size_t)row * 1024 + src_k, &As[buf][tid * 8]);
        }
        #pragma unroll
        for (int i = 0; i < 2; ++i) {
            int idx = i * 256 + tid;
            int row = idx >> 2, kc = idx & 3;
            int src_k = k0 + ((kc ^ ((row >> 1) & 3)) * 8);
            gload_lds16(Bg + (size_t)row * 1024 + src_k, &Bs[buf][idx * 8]);
        }
    };

    STAGE(0, 0);
    __syncthreads();

    for (int t = 0; t < 32; ++t) {
        const int cur = t & 1;
        if (t + 1 < 32) STAGE((t + 1) * 32, cur ^ 1);

        short8 a[4], b[2];
        #pragma unroll
        for (int mi = 0; mi < 4; ++mi) {
            int ra = mi * 16 + l15;
            a[mi] = *(const short8*)&As[cur][ra * 32 + ((lh ^ ((ra >> 1) & 3)) * 8)];
        }
        #pragma unroll
        for (int nj = 0; nj < 2; ++nj) {
            int rb = wid * 32 + nj * 16 + l15;
            b[nj] = *(const short8*)&Bs[cur][rb * 32 + ((lh ^ ((rb >> 1) & 3)) * 8)];
        }
        __builtin_amdgcn_s_setprio(1);
        #pragma unroll
        for (int mi = 0; mi < 4; ++mi)
            #pragma unroll
            for (int nj = 0; nj < 2; ++nj)
                acc[mi][nj] = MFMA16(a[mi], b[nj], acc[mi][nj]);
        __builtin_amdgcn_s_setprio(0);

        __syncthreads();
    }

    #pragma unroll
    for (int mi = 0; mi < 4; ++mi)
        #pragma unroll
        for (int nj = 0; nj < 2; ++nj)
            #pragma unroll
            for (int r2 = 0; r2 < 4; ++r2) {
                int m = bm + mi * 16 + lh * 4 + r2;
                int n = bn + wid * 32 + nj * 16 + l15;
                C[(size_t)m * 1024 + n] = acc[mi][nj][r2];
            }
}

// ---------------------------------------------------------------------------
// Flash attention v5.4 (R14/R16/R18-proven, unchanged): one q-tile per
// block, parity-split KV (LDS-staged K via gload_lds — staging IS the
// coalescing mechanism, R17 lesson), single state, single-buffered Vt,
// dbuf K, exp2 softmax + T13 defer-max, max3 tree, shfl cross-half reduce.
// LDS 52KB -> 3 blk/CU. Grid (32 bh fast, 32 slot), qt = 31 - slot (LPT).
// ---------------------------------------------------------------------------
#define ATTN_STEP(PO, MM, LL)                                                   \
  do {                                                                          \
    f32x16 st;                                                                  \
    _Pragma("unroll") for (int k = 0; k < 16; ++k) st[k] = 0.f;                 \
    __builtin_amdgcn_s_setprio(1);                                              \
    {                                                                           \
      const int keyr = h2 * 32 + l31;                                          \
      const ushort_t* kbase = &Ks_c[cur * 4096 + keyr * 64];                    \
      _Pragma("unroll") for (int dk = 0; dk < 4; ++dk) {                        \
        short8 kf = *(const short8*)(kbase + (((dk * 2 + h) ^ (l31 & 7)) * 8)); \
        st = MFMA32(kf, qf[dk], st);                                            \
      }                                                                         \
    }                                                                           \
    __builtin_amdgcn_s_setprio(0);                                              \
    if (kt == qt) {                                                             \
      const int qloc = sub * 32 + l31;                                          \
      _Pragma("unroll") for (int r = 0; r < 16; ++r) {                          \
        int keyloc = h2 * 32 + (r & 3) + 8 * (r >> 2) + 4 * h;                  \
        if (keyloc > qloc) st[r] = -1e30f;                                      \
      }                                                                         \
    }                                                                           \
    float m0 = fmax3(st[0],  st[1],  st[2]);                                    \
    float m1 = fmax3(st[3],  st[4],  st[5]);                                    \
    float m2 = fmax3(st[6],  st[7],  st[8]);                                    \
    float m3 = fmax3(st[9],  st[10], st[11]);                                   \
    float m4 = fmax3(st[12], st[13], st[14]);                                   \
    float n0 = fmax3(m0, m1, m2);                                               \
    float n1 = fmax3(m3, m4, st[15]);                                           \
    float mt = xhalf_max(fmaxf(n0, n1));                                        \
    if (!__all(mt <= MM + 11.0f)) {    /* T13: rescale only on real growth */   \
      float mnew = fmaxf(MM, mt);                                               \
      float cr = fexp2(MM - mnew);                                              \
      MM = mnew;                                                                \
      LL *= cr;                                                                 \
      _Pragma("unroll") for (int db = 0; db < 2; ++db)                          \
        _Pragma("unroll") for (int k = 0; k < 16; ++k) PO[db][k] *= cr;         \
    }                                                                           \
    _Pragma("unroll") for (int k = 0; k < 16; ++k) st[k] = fexp2(st[k] - MM);   \
    float t8[8];                                                                \
    _Pragma("unroll") for (int k = 0; k < 8; ++k) t8[k] = st[k] + st[k + 8];    \
    _Pragma("unroll") for (int stp = 4; stp >= 1; stp >>= 1)                    \
      _Pragma("unroll") for (int k = 0; k < stp; ++k) t8[k] += t8[k + stp];     \
    LL += xhalf_add(t8[0]);                                                     \
    {                                                                           \
      unsigned w0 = cvt_pk(st[0], st[1]);   unsigned w1 = cvt_pk(st[2], st[3]); \
      unsigned w2 = cvt_pk(st[4], st[5]);   unsigned w3 = cvt_pk(st[6], st[7]); \
      unsigned w4 = cvt_pk(st[8], st[9]);   unsigned w5 = cvt_pk(st[10], st[11]); \
      unsigned w6 = cvt_pk(st[12], st[13]); unsigned w7 = cvt_pk(st[14], st[15]); \
      plswap(w0, w2); plswap(w1, w3); plswap(w4, w6); plswap(w5, w7);           \
      union { unsigned u[4]; short8 s8; } f0, f1;                               \
      f0.u[0] = w0; f0.u[1] = w1; f0.u[2] = w2; f0.u[3] = w3;                   \
      f1.u[0] = w4; f1.u[1] = w5; f1.u[2] = w6; f1.u[3] = w7;                   \
      __builtin_amdgcn_s_setprio(1);                                            \
      _Pragma("unroll") for (int db = 0; db < 2; ++db) {                        \
        const int d = db * 32 + l31;                                            \
        const int ck0 = 4 * h2 + h;                                             \
        short8 vf0 = *(const short8*)&Vt_c[d][((ck0 + (d >> 3)) & 7) * 8];      \
        PO[db] = MFMA32(vf0, f0.s8, PO[db]);                                    \
        const int ck1 = 4 * h2 + 2 + h;                                         \
        short8 vf1 = *(const short8*)&Vt_c[d][((ck1 + (d >> 3)) & 7) * 8];      \
        PO[db] = MFMA32(vf1, f1.s8, PO[db]);                                    \
      }                                                                         \
      __builtin_amdgcn_s_setprio(0);                                            \
    }                                                                           \
  } while (0)

__global__ __launch_bounds__(512, 4) void attn_kernel(
    const ushort_t* __restrict__ Q, const ushort_t* __restrict__ K,
    const ushort_t* __restrict__ V, ushort_t* __restrict__ AO)
{
    __shared__ __align__(16) char smem[52224];
    ushort_t* KsE = (ushort_t*)smem;                          // [2][4096]
    ushort_t (*VtE)[72] = (ushort_t(*)[72])(smem + 16384);    // [64][72]
    ushort_t* KsO = (ushort_t*)(smem + 25600);
    ushort_t (*VtO)[72] = (ushort_t(*)[72])(smem + 41984);
    float* carve = (float*)smem;

    const int tid = threadIdx.x;
    const int lane = tid & 63, wid = tid >> 6;
    const int l31 = lane & 31, h = lane >> 5;
    const int bh = blockIdx.x;                // XCD = bh%8 (bh fast)
    const int qt = 31 - blockIdx.y;           // big blocks first (LPT backfill)
    const int sub = wid & 1, h2 = (wid >> 1) & 1, par = wid >> 2;
    const size_t base = (size_t)bh * (Tn * HDn);
    const int nIter = (qt >> 1) + 1;

    const int s = tid >> 8;
    const int ltid = tid & 255;
    ushort_t* Ks_s = s ? KsO : KsE;
    ushort_t (*Vt_s)[72] = s ? VtO : VtE;
    ushort_t* Ks_c = par ? KsO : KsE;
    ushort_t (*Vt_c)[72] = par ? VtO : VtE;
    const int vkp = (ltid >> 3) * 2, vc = ltid & 7;

    short8 qf[4];
    {
        const ushort_t* qp = Q + base + (size_t)(qt * 64 + sub * 32 + l31) * 64 + h * 8;
        #pragma unroll
        for (int dk = 0; dk < 4; ++dk) qf[dk] = *(const short8*)(qp + dk * 16);
    }

    f32x16 po[2];
    #pragma unroll
    for (int db = 0; db < 2; ++db)
        #pragma unroll
        for (int k = 0; k < 16; ++k) po[db][k] = 0.f;
    float m = -INFINITY, l = 0.f;

    u16x8 va, vb;
    {
        const ushort_t* ks = K + base + (size_t)s * 4096;
        #pragma unroll
        for (int i = 0; i < 2; ++i) {
            int idx = i * 256 + ltid, key = idx >> 3, c = idx & 7;
            gload_lds16(ks + key * 64 + ((c ^ (key & 7)) * 8), &Ks_s[idx * 8]);
        }
        const ushort_t* v0 = V + base + (size_t)s * 4096 + (size_t)vkp * 64 + vc * 8;
        va = *(const u16x8*)v0;
        vb = *(const u16x8*)(v0 + 64);
        #pragma unroll
        for (int j = 0; j < 8; ++j) {
            int d = vc * 8 + j;
            unsigned w = (unsigned)va[j] | ((unsigned)vb[j] << 16);
            int blk = ((vkp >> 3) + (d >> 3)) & 7;
            *(unsigned*)&Vt_s[d][blk * 8 + (vkp & 7)] = w;
        }
    }
    __syncthreads();

    for (int i = 0; i < nIter; ++i) {
        const int cur = i & 1;
        const int ktn = 2 * (i + 1) + s;
        const bool doPf = (ktn <= qt);
        if (doPf) {
            const ushort_t* ks = K + base + (size_t)ktn * 4096;
            #pragma unroll
            for (int ii = 0; ii < 2; ++ii) {
                int idx = ii * 256 + ltid, key = idx >> 3, c = idx & 7;
                gload_lds16(ks + key * 64 + ((c ^ (key & 7)) * 8),
                            &Ks_s[(cur ^ 1) * 4096 + idx * 8]);
            }
            const ushort_t* v0 = V + base + (size_t)ktn * 4096 + (size_t)vkp * 64 + vc * 8;
            va = *(const u16x8*)v0;
            vb = *(const u16x8*)(v0 + 64);
        }

        const int kt = 2 * i + par;
        if (kt <= qt && !(kt == qt && h2 > sub)) {
            ATTN_STEP(po, m, l);
        }

        __syncthreads();                          // all waves done reading Vt
        if (doPf) {
            #pragma unroll
            for (int j = 0; j < 8; ++j) {
                int d = vc * 8 + j;
                unsigned w = (unsigned)va[j] | ((unsigned)vb[j] << 16);
                int blk = ((vkp >> 3) + (d >> 3)) & 7;
                *(unsigned*)&Vt_s[d][blk * 8 + (vkp & 7)] = w;
            }
        }
        __syncthreads();                          // Vt(i+1) ready; K loads drained
    }

    // ---- 4-way merge (par x h2) per sub, one round (log2 domain) ----
    const int b_ = bh >> 4, head = bh & 15;
    if (wid >= 2) {
        float* dstp = carve + (size_t)(wid - 2) * 2176 + lane * 34;
        dstp[0] = m; dstp[1] = l;
        #pragma unroll
        for (int db = 0; db < 2; ++db)
            #pragma unroll
            for (int k = 0; k < 16; ++k) dstp[2 + db * 16 + k] = po[db][k];
    }
    __syncthreads();
    if (wid < 2) {
        const float* p0 = carve + (size_t)(wid + 0) * 2176 + lane * 34;
        const float* p1 = carve + (size_t)(wid + 2) * 2176 + lane * 34;
        const float* p2 = carve + (size_t)(wid + 4) * 2176 + lane * 34;
        float m0 = p0[0], l0 = p0[1], m1 = p1[0], l1 = p1[1], m2 = p2[0], l2 = p2[1];
        float mf = fmaxf(fmaxf(m, m0), fmaxf(m1, m2));
        float c  = fexp2(m - mf), c0 = fexp2(m0 - mf);
        float c1 = fexp2(m1 - mf), c2 = fexp2(m2 - mf);
        float lf = l * c + l0 * c0 + l1 * c1 + l2 * c2;
        float inv = 1.0f / lf;
        const int qg2 = qt * 64 + wid * 32 + l31;
        ushort_t* orow = AO + ((size_t)(b_ * Tn + qg2)) * Dn + head * HDn;
        #pragma unroll
        for (int db = 0; db < 2; ++db) {
            #pragma unroll
            for (int rq = 0; rq < 4; ++rq) {
                u16x4 o4;
                #pragma unroll
                for (int rr = 0; rr < 4; ++rr) {
                    int k = rq * 4 + rr;
                    float v = (po[db][k] * c + p0[2 + db * 16 + k] * c0 +
                               p1[2 + db * 16 + k] * c1 + p2[2 + db * 16 + k] * c2) * inv;
                    o4[rr] = f2b(v);
                }
                *(u16x4*)&orow[db * 32 + 8 * rq + 4 * h] = o4;
            }
        }
    }
}

// ---------------------------------------------------------------------------
extern "C" void kernel_launch(void* const* d_in, const int* in_sizes, int n_in,
                              void* d_out, int out_size, void* d_ws, size_t ws_size,
                              hipStream_t stream)
{
    const float* x     = (const float*)d_in[0];
    const float* Wqkv  = (const float*)d_in[1];
    const float* Wproj = (const float*)d_in[2];
    float* out = (float*)d_out;

    ushort_t* ws = (ushort_t*)d_ws;
    ushort_t* xb     = ws;
    ushort_t* Wqkvt  = xb     + 4194304;
    ushort_t* Wprojt = Wqkvt  + 3145728;
    ushort_t* Qb     = Wprojt + 1048576;
    ushort_t* Kb     = Qb     + 4194304;
    ushort_t* Vb     = Kb     + 4194304;
    ushort_t* AOb    = Vb     + 4194304;

    // merged prep: cast + both weight transposes in ONE launch
    prep_kernel<<<2048 + 4096, 256, 0, stream>>>(x, xb, Wqkv, Wqkvt, Wproj, Wprojt);

    // QKV projection with fused RoPE: BM=64 -> 1536 blocks = 6/CU
    gemm_qkv64_kernel<<<dim3(3072 / 128, 4096 / 64), 256, 0, stream>>>(
        xb, Wqkvt, Qb, Kb, Vb);

    // flash attention: one q-tile per block, big-first dispatch, bh-major
    attn_kernel<<<dim3(Bn * Hn, 32), 512, 0, stream>>>(Qb, Kb, Vb, AOb);

    // output projection: BM=64 tile -> 512 blocks = 2/CU
    gemm_proj64_kernel<<<dim3(8, 64), 256, 0, stream>>>(AOb, Wprojt, out);
}

// Round 22
// 104.427 us; speedup vs baseline: 1.1603x; 1.1603x over previous
//
#include <hip/hip_runtime.h>
#include <hip/hip_bf16.h>
#include <math.h>

// Problem constants
#define Bn  2
#define Tn  2048
#define Dn  1024
#define Hn  16
#define HDn 64
// M = B*T = 4096

typedef __attribute__((ext_vector_type(8))) short short8;
typedef __attribute__((ext_vector_type(8))) unsigned short u16x8;
typedef __attribute__((ext_vector_type(4))) unsigned short u16x4;
typedef __attribute__((ext_vector_type(4))) float f32x4;
typedef __attribute__((ext_vector_type(16))) float f32x16;
typedef unsigned short ushort_t;

#define MFMA16(a, b, c) __builtin_amdgcn_mfma_f32_16x16x32_bf16((a), (b), (c), 0, 0, 0)
#define MFMA32(a, b, c) __builtin_amdgcn_mfma_f32_32x32x16_bf16((a), (b), (c), 0, 0, 0)

__device__ __forceinline__ unsigned short f2b(float f) {
    union { float f; unsigned u; } v; v.f = f;
    unsigned r = (v.u + 0x7FFFu + ((v.u >> 16) & 1u)) >> 16;   // RNE
    return (unsigned short)r;
}
__device__ __forceinline__ void gload_lds16(const void* g, void* l) {
    __builtin_amdgcn_global_load_lds(
        (const __attribute__((address_space(1))) void*)g,
        (__attribute__((address_space(3))) void*)l, 16, 0, 0);
}
__device__ __forceinline__ unsigned cvt_pk(float lo, float hi) {
    unsigned r;
    asm("v_cvt_pk_bf16_f32 %0, %1, %2" : "=v"(r) : "v"(lo), "v"(hi));
    return r;
}
// permlane32_swap with DISTINCT SSA values only (b==a would coalesce registers).
// Inputs must come from compiler-scheduled code, never from an immediately-
// preceding hand-written asm op (R12 hazard lesson).
__device__ __forceinline__ void plswap(unsigned &a, unsigned &b) {
    asm volatile("v_permlane32_swap_b32 %0, %1" : "+v"(a), "+v"(b));
}
// cross-half (lane ^ 32) reductions via shfl — PROVEN form (R5-R19)
__device__ __forceinline__ float xhalf_max(float v) {
    return fmaxf(v, __shfl_xor(v, 32));
}
__device__ __forceinline__ float xhalf_add(float v) {
    return v + __shfl_xor(v, 32);
}
// bare 2^x (scores live in log2 domain; log2e folded into Q scale)
__device__ __forceinline__ float fexp2(float x) {
    float r;
    asm("v_exp_f32 %0, %1" : "=v"(r) : "v"(x));
    return r;
}
__device__ __forceinline__ float fmax3(float a, float b, float c) {
    float r;
    asm("v_max3_f32 %0, %1, %2, %3" : "=v"(r) : "v"(a), "v"(b), "v"(c));
    return r;
}

// ---------------------------------------------------------------------------
// Merged prep: blocks 0..2047 cast x (f32)->bf16 (vectorized);
// blocks 2048..6143 do both weight transposes (branch is block-uniform,
// so the transpose-path __syncthreads is safe).
// ---------------------------------------------------------------------------
__global__ __launch_bounds__(256) void prep_kernel(
    const float* __restrict__ x, ushort_t* __restrict__ xb,
    const float* __restrict__ Wq, ushort_t* __restrict__ Wqt,
    const float* __restrict__ Wp, ushort_t* __restrict__ Wpt)
{
    __shared__ float tile[32][33];
    const int bid = blockIdx.x;
    if (bid < 2048) {
        int i = bid * 256 + threadIdx.x;
        const float4* p = (const float4*)x;
        float4 a = p[i * 2], b = p[i * 2 + 1];
        u16x8 o;
        o[0] = f2b(a.x); o[1] = f2b(a.y); o[2] = f2b(a.z); o[3] = f2b(a.w);
        o[4] = f2b(b.x); o[5] = f2b(b.y); o[6] = f2b(b.z); o[7] = f2b(b.w);
        *(u16x8*)&xb[i * 8] = o;
        return;
    }
    const int idx = bid - 2048;               // 0..4095
    const int bx = idx & 127, ky = idx >> 7;  // 128 x-blocks, 32 k-blocks
    const float* W;
    ushort_t* Wt;
    int N, n0;
    if (bx < 96) { W = Wq; Wt = Wqt; N = 3072; n0 = bx * 32; }
    else         { W = Wp; Wt = Wpt; N = 1024; n0 = (bx - 96) * 32; }
    const int k0 = ky * 32;
    const int tx = threadIdx.x & 31, ty = threadIdx.x >> 5;
    #pragma unroll
    for (int i = 0; i < 4; ++i)
        tile[ty + i * 8][tx] = W[(size_t)(k0 + ty + i * 8) * N + n0 + tx];
    __syncthreads();
    #pragma unroll
    for (int i = 0; i < 4; ++i)
        Wt[(size_t)(n0 + ty + i * 8) * 1024 + k0 + tx] = f2b(tile[tx][ty + i * 8]);
}

// ---------------------------------------------------------------------------
// bf16 MFMA GEMM — R16/R18 form (best proven): BK=32, T3 2-phase prefetch,
// conflict-free row-pair XOR swizzle, 2-D XCD chunking, sincos RoPE epi.
// BOTH instantiations kept compiled (rule #19: preserve codegen context);
// only <0> is launched — <1> replaced at launch by gemm_proj64_kernel.
// NOTE (R21 lesson): do NOT shrink BM for occupancy here — halving per-wave
// MFMA work per barrier + doubled B-panel refetch loses more than 6/CU gains.
// ---------------------------------------------------------------------------
template <int EPI>
__global__ __launch_bounds__(256) void gemm_kernel(
    const ushort_t* __restrict__ A, const ushort_t* __restrict__ Bt,
    ushort_t* __restrict__ Qo, ushort_t* __restrict__ Ko, ushort_t* __restrict__ Vo,
    float* __restrict__ C, int Ncols)
{
    __shared__ __align__(16) ushort_t As[2][128 * 32];
    __shared__ __align__(16) ushort_t Bs[2][128 * 32];
    const int tid  = threadIdx.x;
    const int lane = tid & 63, wid = tid >> 6;
    const int l15 = lane & 15, lh = lane >> 4;
    const int wr = wid >> 1, wc = wid & 1;

    const int nbx = gridDim.x;
    const int bid = blockIdx.y * nbx + blockIdx.x;
    const int xcd = bid & 7, r = bid >> 3;
    const int xm = xcd >> 1, xn = xcd & 1;
    const int bmc = gridDim.y >> 2;
    const int bnc = nbx >> 1;
    const int rm = r % bmc, rn = r / bmc;
    const int bm = (xm * bmc + rm) * 128;
    const int bn = (xn * bnc + rn) * 128;

    f32x4 acc[4][4];
    #pragma unroll
    for (int i = 0; i < 4; ++i)
        #pragma unroll
        for (int j = 0; j < 4; ++j) acc[i][j] = (f32x4){0.f, 0.f, 0.f, 0.f};

    const ushort_t* Ag = A  + (size_t)bm * 1024;
    const ushort_t* Bg = Bt + (size_t)bn * 1024;

    auto STAGE = [&](int k0, int buf) {
        #pragma unroll
        for (int i = 0; i < 2; ++i) {
            int idx = i * 256 + tid;
            int row = idx >> 2, kc = idx & 3;
            int src_k = k0 + ((kc ^ ((row >> 1) & 3)) * 8);   // row-pair XOR
            gload_lds16(Ag + (size_t)row * 1024 + src_k, &As[buf][idx * 8]);
            gload_lds16(Bg + (size_t)row * 1024 + src_k, &Bs[buf][idx * 8]);
        }
    };

    STAGE(0, 0);
    __syncthreads();

    for (int t = 0; t < 32; ++t) {
        const int cur = t & 1;
        if (t + 1 < 32) STAGE((t + 1) * 32, cur ^ 1);

        short8 a[4], b[4];
        #pragma unroll
        for (int mi = 0; mi < 4; ++mi) {
            int ra = wr * 64 + mi * 16 + l15;
            a[mi] = *(const short8*)&As[cur][ra * 32 + ((lh ^ ((ra >> 1) & 3)) * 8)];
        }
        #pragma unroll
        for (int nj = 0; nj < 4; ++nj) {
            int rb = wc * 64 + nj * 16 + l15;
            b[nj] = *(const short8*)&Bs[cur][rb * 32 + ((lh ^ ((rb >> 1) & 3)) * 8)];
        }
        __builtin_amdgcn_s_setprio(1);
        #pragma unroll
        for (int mi = 0; mi < 4; ++mi)
            #pragma unroll
            for (int nj = 0; nj < 4; ++nj)
                acc[mi][nj] = MFMA16(a[mi], b[nj], acc[mi][nj]);
        __builtin_amdgcn_s_setprio(0);

        __syncthreads();
    }

    if (EPI == 0) {
        const int n0 = bn + wc * 64;
        const int i3 = n0 >> 10;              // 0=q, 1=k, 2=v
        const int hh = (n0 >> 6) & 15;
        if (i3 == 2) {
            #pragma unroll
            for (int mi = 0; mi < 4; ++mi)
                #pragma unroll
                for (int r2 = 0; r2 < 4; ++r2) {
                    int m = bm + wr * 64 + mi * 16 + lh * 4 + r2;
                    int b_ = m >> 11, t = m & 2047;
                    size_t ob = ((size_t)((b_ * Hn + hh) * Tn) + t) * HDn;
                    #pragma unroll
                    for (int nj = 0; nj < 4; ++nj)
                        Vo[ob + nj * 16 + l15] = f2b(acc[mi][nj][r2]);
                }
        } else {
            ushort_t* dst = i3 ? Ko : Qo;
            // q scale = 1/sqrt(HD) * log2(e)  -> scores in log2 domain
            const float sc = i3 ? 1.0f : 0.18033688f;
            const float inv0 = __powf(10000.0f, -(float)l15 * (1.0f / 32.0f));
            const float inv1 = __powf(10000.0f, -(float)(16 + l15) * (1.0f / 32.0f));
            #pragma unroll
            for (int mi = 0; mi < 4; ++mi)
                #pragma unroll
                for (int r2 = 0; r2 < 4; ++r2) {
                    int m = bm + wr * 64 + mi * 16 + lh * 4 + r2;
                    int b_ = m >> 11, t = m & 2047;
                    size_t ob = ((size_t)((b_ * Hn + hh) * Tn) + t) * HDn;
                    float tf = (float)t;
                    #pragma unroll
                    for (int nj = 0; nj < 2; ++nj) {
                        float fr = tf * (nj ? inv1 : inv0);
                        float cc, ss;
                        __sincosf(fr, &ss, &cc);
                        float v0 = acc[mi][nj][r2], v1 = acc[mi][nj + 2][r2];
                        int j = nj * 16 + l15;
                        dst[ob + j]      = f2b((v0 * cc - v1 * ss) * sc);
                        dst[ob + j + 32] = f2b((v1 * cc + v0 * ss) * sc);
                    }
                }
        }
    } else {
        #pragma unroll
        for (int mi = 0; mi < 4; ++mi)
            #pragma unroll
            for (int nj = 0; nj < 4; ++nj)
                #pragma unroll
                for (int r2 = 0; r2 < 4; ++r2) {
                    int m = bm + wr * 64 + mi * 16 + lh * 4 + r2;
                    int n = bn + wc * 64 + nj * 16 + l15;
                    C[(size_t)m * 1024 + n] = acc[mi][nj][r2];
                }
    }
}
// keep <1> compiled to preserve the module's codegen context (rule #19)
template __global__ void gemm_kernel<1>(
    const ushort_t* __restrict__, const ushort_t* __restrict__,
    ushort_t* __restrict__, ushort_t* __restrict__, ushort_t* __restrict__,
    float* __restrict__, int);

// ---------------------------------------------------------------------------
// Output projection GEMM, BM=64 x BN=128: grid (8, 64) = 512 blocks = 2/CU
// (the 128x128 version was 256 blocks = 1/CU -> zero inter-block latency
// hiding). 4 waves = 1x4 column groups; acc[4][2] (32 VGPR). Same proven
// BK=32 + 2-phase prefetch + row-pair XOR swizzle + 2-D XCD chunking.
// ---------------------------------------------------------------------------
__global__ __launch_bounds__(256) void gemm_proj64_kernel(
    const ushort_t* __restrict__ A, const ushort_t* __restrict__ Bt,
    float* __restrict__ C)
{
    __shared__ __align__(16) ushort_t As[2][64 * 32];    // 4 KB each
    __shared__ __align__(16) ushort_t Bs[2][128 * 32];   // 8 KB each
    const int tid  = threadIdx.x;
    const int lane = tid & 63, wid = tid >> 6;           // wid 0..3 = col group
    const int l15 = lane & 15, lh = lane >> 4;

    // 2-D XCD chunk mapping: grid (8, 64); bmc = 16, bnc = 4
    const int nbx = gridDim.x;
    const int bid = blockIdx.y * nbx + blockIdx.x;
    const int xcd = bid & 7, r = bid >> 3;
    const int xm = xcd >> 1, xn = xcd & 1;
    const int bmc = gridDim.y >> 2;
    const int bnc = nbx >> 1;
    const int rm = r % bmc, rn = r / bmc;
    const int bm = (xm * bmc + rm) * 64;
    const int bn = (xn * bnc + rn) * 128;

    f32x4 acc[4][2];
    #pragma unroll
    for (int i = 0; i < 4; ++i)
        #pragma unroll
        for (int j = 0; j < 2; ++j) acc[i][j] = (f32x4){0.f, 0.f, 0.f, 0.f};

    const ushort_t* Ag = A  + (size_t)bm * 1024;
    const ushort_t* Bg = Bt + (size_t)bn * 1024;

    auto STAGE = [&](int k0, int buf) {
        {   // A tile: 64 rows x 32 k = 256 chunks, 1 per thread
            int row = tid >> 2, kc = tid & 3;
            int src_k = k0 + ((kc ^ ((row >> 1) & 3)) * 8);
            gload_lds16(Ag + (size_t)row * 1024 + src_k, &As[buf][tid * 8]);
        }
        #pragma unroll
        for (int i = 0; i < 2; ++i) {   // B tile: 128 rows x 32 k = 512 chunks
            int idx = i * 256 + tid;
            int row = idx >> 2, kc = idx & 3;
            int src_k = k0 + ((kc ^ ((row >> 1) & 3)) * 8);
            gload_lds16(Bg + (size_t)row * 1024 + src_k, &Bs[buf][idx * 8]);
        }
    };

    STAGE(0, 0);
    __syncthreads();

    for (int t = 0; t < 32; ++t) {
        const int cur = t & 1;
        if (t + 1 < 32) STAGE((t + 1) * 32, cur ^ 1);

        short8 a[4], b[2];
        #pragma unroll
        for (int mi = 0; mi < 4; ++mi) {
            int ra = mi * 16 + l15;
            a[mi] = *(const short8*)&As[cur][ra * 32 + ((lh ^ ((ra >> 1) & 3)) * 8)];
        }
        #pragma unroll
        for (int nj = 0; nj < 2; ++nj) {
            int rb = wid * 32 + nj * 16 + l15;
            b[nj] = *(const short8*)&Bs[cur][rb * 32 + ((lh ^ ((rb >> 1) & 3)) * 8)];
        }
        __builtin_amdgcn_s_setprio(1);
        #pragma unroll
        for (int mi = 0; mi < 4; ++mi)
            #pragma unroll
            for (int nj = 0; nj < 2; ++nj)
                acc[mi][nj] = MFMA16(a[mi], b[nj], acc[mi][nj]);
        __builtin_amdgcn_s_setprio(0);

        __syncthreads();
    }

    #pragma unroll
    for (int mi = 0; mi < 4; ++mi)
        #pragma unroll
        for (int nj = 0; nj < 2; ++nj)
            #pragma unroll
            for (int r2 = 0; r2 < 4; ++r2) {
                int m = bm + mi * 16 + lh * 4 + r2;
                int n = bn + wid * 32 + nj * 16 + l15;
                C[(size_t)m * 1024 + n] = acc[mi][nj][r2];
            }
}

// ---------------------------------------------------------------------------
// Flash attention v5.4 (R14/R16/R18-proven, unchanged): one q-tile per
// block, parity-split KV (LDS-staged K via gload_lds — staging IS the
// coalescing mechanism, R17 lesson), single state, single-buffered Vt,
// dbuf K, exp2 softmax + T13 defer-max, max3 tree, shfl cross-half reduce.
// LDS 52KB -> 3 blk/CU. Grid (32 bh fast, 32 slot), qt = 31 - slot (LPT).
// ---------------------------------------------------------------------------
#define ATTN_STEP(PO, MM, LL)                                                   \
  do {                                                                          \
    f32x16 st;                                                                  \
    _Pragma("unroll") for (int k = 0; k < 16; ++k) st[k] = 0.f;                 \
    __builtin_amdgcn_s_setprio(1);                                              \
    {                                                                           \
      const int keyr = h2 * 32 + l31;                                          \
      const ushort_t* kbase = &Ks_c[cur * 4096 + keyr * 64];                    \
      _Pragma("unroll") for (int dk = 0; dk < 4; ++dk) {                        \
        short8 kf = *(const short8*)(kbase + (((dk * 2 + h) ^ (l31 & 7)) * 8)); \
        st = MFMA32(kf, qf[dk], st);                                            \
      }                                                                         \
    }                                                                           \
    __builtin_amdgcn_s_setprio(0);                                              \
    if (kt == qt) {                                                             \
      const int qloc = sub * 32 + l31;                                          \
      _Pragma("unroll") for (int r = 0; r < 16; ++r) {                          \
        int keyloc = h2 * 32 + (r & 3) + 8 * (r >> 2) + 4 * h;                  \
        if (keyloc > qloc) st[r] = -1e30f;                                      \
      }                                                                         \
    }                                                                           \
    float m0 = fmax3(st[0],  st[1],  st[2]);                                    \
    float m1 = fmax3(st[3],  st[4],  st[5]);                                    \
    float m2 = fmax3(st[6],  st[7],  st[8]);                                    \
    float m3 = fmax3(st[9],  st[10], st[11]);                                   \
    float m4 = fmax3(st[12], st[13], st[14]);                                   \
    float n0 = fmax3(m0, m1, m2);                                               \
    float n1 = fmax3(m3, m4, st[15]);                                           \
    float mt = xhalf_max(fmaxf(n0, n1));                                        \
    if (!__all(mt <= MM + 11.0f)) {    /* T13: rescale only on real growth */   \
      float mnew = fmaxf(MM, mt);                                               \
      float cr = fexp2(MM - mnew);                                              \
      MM = mnew;                                                                \
      LL *= cr;                                                                 \
      _Pragma("unroll") for (int db = 0; db < 2; ++db)                          \
        _Pragma("unroll") for (int k = 0; k < 16; ++k) PO[db][k] *= cr;         \
    }                                                                           \
    _Pragma("unroll") for (int k = 0; k < 16; ++k) st[k] = fexp2(st[k] - MM);   \
    float t8[8];                                                                \
    _Pragma("unroll") for (int k = 0; k < 8; ++k) t8[k] = st[k] + st[k + 8];    \
    _Pragma("unroll") for (int stp = 4; stp >= 1; stp >>= 1)                    \
      _Pragma("unroll") for (int k = 0; k < stp; ++k) t8[k] += t8[k + stp];     \
    LL += xhalf_add(t8[0]);                                                     \
    {                                                                           \
      unsigned w0 = cvt_pk(st[0], st[1]);   unsigned w1 = cvt_pk(st[2], st[3]); \
      unsigned w2 = cvt_pk(st[4], st[5]);   unsigned w3 = cvt_pk(st[6], st[7]); \
      unsigned w4 = cvt_pk(st[8], st[9]);   unsigned w5 = cvt_pk(st[10], st[11]); \
      unsigned w6 = cvt_pk(st[12], st[13]); unsigned w7 = cvt_pk(st[14], st[15]); \
      plswap(w0, w2); plswap(w1, w3); plswap(w4, w6); plswap(w5, w7);           \
      union { unsigned u[4]; short8 s8; } f0, f1;                               \
      f0.u[0] = w0; f0.u[1] = w1; f0.u[2] = w2; f0.u[3] = w3;                   \
      f1.u[0] = w4; f1.u[1] = w5; f1.u[2] = w6; f1.u[3] = w7;                   \
      __builtin_amdgcn_s_setprio(1);                                            \
      _Pragma("unroll") for (int db = 0; db < 2; ++db) {                        \
        const int d = db * 32 + l31;                                            \
        const int ck0 = 4 * h2 + h;                                             \
        short8 vf0 = *(const short8*)&Vt_c[d][((ck0 + (d >> 3)) & 7) * 8];      \
        PO[db] = MFMA32(vf0, f0.s8, PO[db]);                                    \
        const int ck1 = 4 * h2 + 2 + h;                                         \
        short8 vf1 = *(const short8*)&Vt_c[d][((ck1 + (d >> 3)) & 7) * 8];      \
        PO[db] = MFMA32(vf1, f1.s8, PO[db]);                                    \
      }                                                                         \
      __builtin_amdgcn_s_setprio(0);                                            \
    }                                                                           \
  } while (0)

__global__ __launch_bounds__(512, 4) void attn_kernel(
    const ushort_t* __restrict__ Q, const ushort_t* __restrict__ K,
    const ushort_t* __restrict__ V, ushort_t* __restrict__ AO)
{
    __shared__ __align__(16) char smem[52224];
    ushort_t* KsE = (ushort_t*)smem;                          // [2][4096]
    ushort_t (*VtE)[72] = (ushort_t(*)[72])(smem + 16384);    // [64][72]
    ushort_t* KsO = (ushort_t*)(smem + 25600);
    ushort_t (*VtO)[72] = (ushort_t(*)[72])(smem + 41984);
    float* carve = (float*)smem;

    const int tid = threadIdx.x;
    const int lane = tid & 63, wid = tid >> 6;
    const int l31 = lane & 31, h = lane >> 5;
    const int bh = blockIdx.x;                // XCD = bh%8 (bh fast)
    const int qt = 31 - blockIdx.y;           // big blocks first (LPT backfill)
    const int sub = wid & 1, h2 = (wid >> 1) & 1, par = wid >> 2;
    const size_t base = (size_t)bh * (Tn * HDn);
    const int nIter = (qt >> 1) + 1;

    const int s = tid >> 8;
    const int ltid = tid & 255;
    ushort_t* Ks_s = s ? KsO : KsE;
    ushort_t (*Vt_s)[72] = s ? VtO : VtE;
    ushort_t* Ks_c = par ? KsO : KsE;
    ushort_t (*Vt_c)[72] = par ? VtO : VtE;
    const int vkp = (ltid >> 3) * 2, vc = ltid & 7;

    short8 qf[4];
    {
        const ushort_t* qp = Q + base + (size_t)(qt * 64 + sub * 32 + l31) * 64 + h * 8;
        #pragma unroll
        for (int dk = 0; dk < 4; ++dk) qf[dk] = *(const short8*)(qp + dk * 16);
    }

    f32x16 po[2];
    #pragma unroll
    for (int db = 0; db < 2; ++db)
        #pragma unroll
        for (int k = 0; k < 16; ++k) po[db][k] = 0.f;
    float m = -INFINITY, l = 0.f;

    u16x8 va, vb;
    {
        const ushort_t* ks = K + base + (size_t)s * 4096;
        #pragma unroll
        for (int i = 0; i < 2; ++i) {
            int idx = i * 256 + ltid, key = idx >> 3, c = idx & 7;
            gload_lds16(ks + key * 64 + ((c ^ (key & 7)) * 8), &Ks_s[idx * 8]);
        }
        const ushort_t* v0 = V + base + (size_t)s * 4096 + (size_t)vkp * 64 + vc * 8;
        va = *(const u16x8*)v0;
        vb = *(const u16x8*)(v0 + 64);
        #pragma unroll
        for (int j = 0; j < 8; ++j) {
            int d = vc * 8 + j;
            unsigned w = (unsigned)va[j] | ((unsigned)vb[j] << 16);
            int blk = ((vkp >> 3) + (d >> 3)) & 7;
            *(unsigned*)&Vt_s[d][blk * 8 + (vkp & 7)] = w;
        }
    }
    __syncthreads();

    for (int i = 0; i < nIter; ++i) {
        const int cur = i & 1;
        const int ktn = 2 * (i + 1) + s;
        const bool doPf = (ktn <= qt);
        if (doPf) {
            const ushort_t* ks = K + base + (size_t)ktn * 4096;
            #pragma unroll
            for (int ii = 0; ii < 2; ++ii) {
                int idx = ii * 256 + ltid, key = idx >> 3, c = idx & 7;
                gload_lds16(ks + key * 64 + ((c ^ (key & 7)) * 8),
                            &Ks_s[(cur ^ 1) * 4096 + idx * 8]);
            }
            const ushort_t* v0 = V + base + (size_t)ktn * 4096 + (size_t)vkp * 64 + vc * 8;
            va = *(const u16x8*)v0;
            vb = *(const u16x8*)(v0 + 64);
        }

        const int kt = 2 * i + par;
        if (kt <= qt && !(kt == qt && h2 > sub)) {
            ATTN_STEP(po, m, l);
        }

        __syncthreads();                          // all waves done reading Vt
        if (doPf) {
            #pragma unroll
            for (int j = 0; j < 8; ++j) {
                int d = vc * 8 + j;
                unsigned w = (unsigned)va[j] | ((unsigned)vb[j] << 16);
                int blk = ((vkp >> 3) + (d >> 3)) & 7;
                *(unsigned*)&Vt_s[d][blk * 8 + (vkp & 7)] = w;
            }
        }
        __syncthreads();                          // Vt(i+1) ready; K loads drained
    }

    // ---- 4-way merge (par x h2) per sub, one round (log2 domain) ----
    const int b_ = bh >> 4, head = bh & 15;
    if (wid >= 2) {
        float* dstp = carve + (size_t)(wid - 2) * 2176 + lane * 34;
        dstp[0] = m; dstp[1] = l;
        #pragma unroll
        for (int db = 0; db < 2; ++db)
            #pragma unroll
            for (int k = 0; k < 16; ++k) dstp[2 + db * 16 + k] = po[db][k];
    }
    __syncthreads();
    if (wid < 2) {
        const float* p0 = carve + (size_t)(wid + 0) * 2176 + lane * 34;
        const float* p1 = carve + (size_t)(wid + 2) * 2176 + lane * 34;
        const float* p2 = carve + (size_t)(wid + 4) * 2176 + lane * 34;
        float m0 = p0[0], l0 = p0[1], m1 = p1[0], l1 = p1[1], m2 = p2[0], l2 = p2[1];
        float mf = fmaxf(fmaxf(m, m0), fmaxf(m1, m2));
        float c  = fexp2(m - mf), c0 = fexp2(m0 - mf);
        float c1 = fexp2(m1 - mf), c2 = fexp2(m2 - mf);
        float lf = l * c + l0 * c0 + l1 * c1 + l2 * c2;
        float inv = 1.0f / lf;
        const int qg2 = qt * 64 + wid * 32 + l31;
        ushort_t* orow = AO + ((size_t)(b_ * Tn + qg2)) * Dn + head * HDn;
        #pragma unroll
        for (int db = 0; db < 2; ++db) {
            #pragma unroll
            for (int rq = 0; rq < 4; ++rq) {
                u16x4 o4;
                #pragma unroll
                for (int rr = 0; rr < 4; ++rr) {
                    int k = rq * 4 + rr;
                    float v = (po[db][k] * c + p0[2 + db * 16 + k] * c0 +
                               p1[2 + db * 16 + k] * c1 + p2[2 + db * 16 + k] * c2) * inv;
                    o4[rr] = f2b(v);
                }
                *(u16x4*)&orow[db * 32 + 8 * rq + 4 * h] = o4;
            }
        }
    }
}

// ---------------------------------------------------------------------------
extern "C" void kernel_launch(void* const* d_in, const int* in_sizes, int n_in,
                              void* d_out, int out_size, void* d_ws, size_t ws_size,
                              hipStream_t stream)
{
    const float* x     = (const float*)d_in[0];
    const float* Wqkv  = (const float*)d_in[1];
    const float* Wproj = (const float*)d_in[2];
    float* out = (float*)d_out;

    ushort_t* ws = (ushort_t*)d_ws;
    ushort_t* xb     = ws;
    ushort_t* Wqkvt  = xb     + 4194304;
    ushort_t* Wprojt = Wqkvt  + 3145728;
    ushort_t* Qb     = Wprojt + 1048576;
    ushort_t* Kb     = Qb     + 4194304;
    ushort_t* Vb     = Kb     + 4194304;
    ushort_t* AOb    = Vb     + 4194304;

    // merged prep: cast + both weight transposes in ONE launch
    prep_kernel<<<2048 + 4096, 256, 0, stream>>>(x, xb, Wqkv, Wqkvt, Wproj, Wprojt);

    // QKV projection with fused RoPE (+ log2e folded into q scale)
    gemm_kernel<0><<<dim3(3072 / 128, 4096 / 128), 256, 0, stream>>>(
        xb, Wqkvt, Qb, Kb, Vb, nullptr, 3072);

    // flash attention: one q-tile per block, big-first dispatch, bh-major
    attn_kernel<<<dim3(Bn * Hn, 32), 512, 0, stream>>>(Qb, Kb, Vb, AOb);

    // output projection: BM=64 tile -> 512 blocks = 2/CU (was 256 = 1/CU)
    gemm_proj64_kernel<<<dim3(8, 64), 256, 0, stream>>>(AOb, Wprojt, out);
}

// Round 23
// 102.577 us; speedup vs baseline: 1.1812x; 1.0180x over previous
//
#include <hip/hip_runtime.h>
#include <hip/hip_bf16.h>
#include <math.h>

// Problem constants
#define Bn  2
#define Tn  2048
#define Dn  1024
#define Hn  16
#define HDn 64
// M = B*T = 4096

typedef __attribute__((ext_vector_type(8))) short short8;
typedef __attribute__((ext_vector_type(8))) unsigned short u16x8;
typedef __attribute__((ext_vector_type(4))) unsigned short u16x4;
typedef __attribute__((ext_vector_type(4))) float f32x4;
typedef __attribute__((ext_vector_type(16))) float f32x16;
typedef unsigned short ushort_t;

#define MFMA16(a, b, c) __builtin_amdgcn_mfma_f32_16x16x32_bf16((a), (b), (c), 0, 0, 0)
#define MFMA32(a, b, c) __builtin_amdgcn_mfma_f32_32x32x16_bf16((a), (b), (c), 0, 0, 0)

__device__ __forceinline__ unsigned short f2b(float f) {
    union { float f; unsigned u; } v; v.f = f;
    unsigned r = (v.u + 0x7FFFu + ((v.u >> 16) & 1u)) >> 16;   // RNE
    return (unsigned short)r;
}
__device__ __forceinline__ void gload_lds16(const void* g, void* l) {
    __builtin_amdgcn_global_load_lds(
        (const __attribute__((address_space(1))) void*)g,
        (__attribute__((address_space(3))) void*)l, 16, 0, 0);
}
__device__ __forceinline__ unsigned cvt_pk(float lo, float hi) {
    unsigned r;
    asm("v_cvt_pk_bf16_f32 %0, %1, %2" : "=v"(r) : "v"(lo), "v"(hi));
    return r;
}
// permlane32_swap with DISTINCT SSA values only (b==a would coalesce registers).
// Inputs must come from compiler-scheduled code, never from an immediately-
// preceding hand-written asm op (R12 hazard lesson).
__device__ __forceinline__ void plswap(unsigned &a, unsigned &b) {
    asm volatile("v_permlane32_swap_b32 %0, %1" : "+v"(a), "+v"(b));
}
// cross-half (lane ^ 32) reductions via shfl — PROVEN form (R5-R22)
__device__ __forceinline__ float xhalf_max(float v) {
    return fmaxf(v, __shfl_xor(v, 32));
}
__device__ __forceinline__ float xhalf_add(float v) {
    return v + __shfl_xor(v, 32);
}
// bare 2^x (scores live in log2 domain; log2e folded into Q scale)
__device__ __forceinline__ float fexp2(float x) {
    float r;
    asm("v_exp_f32 %0, %1" : "=v"(r) : "v"(x));
    return r;
}
__device__ __forceinline__ float fmax3(float a, float b, float c) {
    float r;
    asm("v_max3_f32 %0, %1, %2, %3" : "=v"(r) : "v"(a), "v"(b), "v"(c));
    return r;
}

// ---------------------------------------------------------------------------
// Merged prep: blocks 0..2047 cast x (f32)->bf16 (vectorized);
// blocks 2048..6143 do both weight transposes (branch is block-uniform,
// so the transpose-path __syncthreads is safe).
// ---------------------------------------------------------------------------
__global__ __launch_bounds__(256) void prep_kernel(
    const float* __restrict__ x, ushort_t* __restrict__ xb,
    const float* __restrict__ Wq, ushort_t* __restrict__ Wqt,
    const float* __restrict__ Wp, ushort_t* __restrict__ Wpt)
{
    __shared__ float tile[32][33];
    const int bid = blockIdx.x;
    if (bid < 2048) {
        int i = bid * 256 + threadIdx.x;
        const float4* p = (const float4*)x;
        float4 a = p[i * 2], b = p[i * 2 + 1];
        u16x8 o;
        o[0] = f2b(a.x); o[1] = f2b(a.y); o[2] = f2b(a.z); o[3] = f2b(a.w);
        o[4] = f2b(b.x); o[5] = f2b(b.y); o[6] = f2b(b.z); o[7] = f2b(b.w);
        *(u16x8*)&xb[i * 8] = o;
        return;
    }
    const int idx = bid - 2048;               // 0..4095
    const int bx = idx & 127, ky = idx >> 7;  // 128 x-blocks, 32 k-blocks
    const float* W;
    ushort_t* Wt;
    int N, n0;
    if (bx < 96) { W = Wq; Wt = Wqt; N = 3072; n0 = bx * 32; }
    else         { W = Wp; Wt = Wpt; N = 1024; n0 = (bx - 96) * 32; }
    const int k0 = ky * 32;
    const int tx = threadIdx.x & 31, ty = threadIdx.x >> 5;
    #pragma unroll
    for (int i = 0; i < 4; ++i)
        tile[ty + i * 8][tx] = W[(size_t)(k0 + ty + i * 8) * N + n0 + tx];
    __syncthreads();
    #pragma unroll
    for (int i = 0; i < 4; ++i)
        Wt[(size_t)(n0 + ty + i * 8) * 1024 + k0 + tx] = f2b(tile[tx][ty + i * 8]);
}

// ---------------------------------------------------------------------------
// bf16 MFMA GEMM — R16 tile/swizzle/XCD structure + T4 counted-vmcnt
// 3-buffer pipeline: prologue stages tiles 0,1; iter t issues STAGE(t+2),
// waits vmcnt(8) (tiles t+1,t+2 STAY IN FLIGHT across the barrier; tile t's
// 4 loads verified landed — m135 in-order drain), raw s_barrier, compute,
// raw s_barrier (separates this iter's reads of buf[t%3] from next iter's
// STAGE(t+3) writes to the same buffer). sched_barrier(0) prevents hipcc
// hoisting LDS reads across the raw barriers (rule #18 hazard class).
// LDS 48 KB -> still 3 blocks/CU. Sincos RoPE epilogue verbatim (R13).
// ---------------------------------------------------------------------------
template <int EPI>
__global__ __launch_bounds__(256) void gemm_kernel(
    const ushort_t* __restrict__ A, const ushort_t* __restrict__ Bt,
    ushort_t* __restrict__ Qo, ushort_t* __restrict__ Ko, ushort_t* __restrict__ Vo,
    float* __restrict__ C, int Ncols)
{
    __shared__ __align__(16) ushort_t As[3][128 * 32];
    __shared__ __align__(16) ushort_t Bs[3][128 * 32];
    const int tid  = threadIdx.x;
    const int lane = tid & 63, wid = tid >> 6;
    const int l15 = lane & 15, lh = lane >> 4;
    const int wr = wid >> 1, wc = wid & 1;

    const int nbx = gridDim.x;
    const int bid = blockIdx.y * nbx + blockIdx.x;
    const int xcd = bid & 7, r = bid >> 3;
    const int xm = xcd >> 1, xn = xcd & 1;
    const int bmc = gridDim.y >> 2;
    const int bnc = nbx >> 1;
    const int rm = r % bmc, rn = r / bmc;
    const int bm = (xm * bmc + rm) * 128;
    const int bn = (xn * bnc + rn) * 128;

    f32x4 acc[4][4];
    #pragma unroll
    for (int i = 0; i < 4; ++i)
        #pragma unroll
        for (int j = 0; j < 4; ++j) acc[i][j] = (f32x4){0.f, 0.f, 0.f, 0.f};

    const ushort_t* Ag = A  + (size_t)bm * 1024;
    const ushort_t* Bg = Bt + (size_t)bn * 1024;

    // 4 gload_lds per thread per STAGE (2 iters x A,B)
    auto STAGE = [&](int k0, int buf) {
        #pragma unroll
        for (int i = 0; i < 2; ++i) {
            int idx = i * 256 + tid;
            int row = idx >> 2, kc = idx & 3;
            int src_k = k0 + ((kc ^ ((row >> 1) & 3)) * 8);   // row-pair XOR
            gload_lds16(Ag + (size_t)row * 1024 + src_k, &As[buf][idx * 8]);
            gload_lds16(Bg + (size_t)row * 1024 + src_k, &Bs[buf][idx * 8]);
        }
    };

    STAGE(0, 0);
    STAGE(32, 1);                 // 8 loads/thread outstanding

    int cur = 0, nx2 = 2;         // cur = t%3, nx2 = (t+2)%3
    for (int t = 0; t < 32; ++t) {
        if (t + 2 < 32) {
            STAGE((t + 2) * 32, nx2);                       // 12 outstanding
            asm volatile("s_waitcnt vmcnt(8)" ::: "memory"); // tile t landed
        } else if (t + 1 < 32) {
            asm volatile("s_waitcnt vmcnt(4)" ::: "memory");
        } else {
            asm volatile("s_waitcnt vmcnt(0)" ::: "memory");
        }
        __builtin_amdgcn_s_barrier();        // all threads' tile-t loads landed
        __builtin_amdgcn_sched_barrier(0);   // no LDS-read hoisting above barrier

        short8 a[4], b[4];
        #pragma unroll
        for (int mi = 0; mi < 4; ++mi) {
            int ra = wr * 64 + mi * 16 + l15;
            a[mi] = *(const short8*)&As[cur][ra * 32 + ((lh ^ ((ra >> 1) & 3)) * 8)];
        }
        #pragma unroll
        for (int nj = 0; nj < 4; ++nj) {
            int rb = wc * 64 + nj * 16 + l15;
            b[nj] = *(const short8*)&Bs[cur][rb * 32 + ((lh ^ ((rb >> 1) & 3)) * 8)];
        }
        __builtin_amdgcn_s_setprio(1);
        #pragma unroll
        for (int mi = 0; mi < 4; ++mi)
            #pragma unroll
            for (int nj = 0; nj < 4; ++nj)
                acc[mi][nj] = MFMA16(a[mi], b[nj], acc[mi][nj]);
        __builtin_amdgcn_s_setprio(0);

        __builtin_amdgcn_sched_barrier(0);
        __builtin_amdgcn_s_barrier();        // reads of buf[cur] done before
                                             // next iter's STAGE overwrites it
        cur = (cur == 2) ? 0 : cur + 1;
        nx2 = (nx2 == 2) ? 0 : nx2 + 1;
    }

    if (EPI == 0) {
        const int n0 = bn + wc * 64;
        const int i3 = n0 >> 10;              // 0=q, 1=k, 2=v
        const int hh = (n0 >> 6) & 15;
        if (i3 == 2) {
            #pragma unroll
            for (int mi = 0; mi < 4; ++mi)
                #pragma unroll
                for (int r2 = 0; r2 < 4; ++r2) {
                    int m = bm + wr * 64 + mi * 16 + lh * 4 + r2;
                    int b_ = m >> 11, t = m & 2047;
                    size_t ob = ((size_t)((b_ * Hn + hh) * Tn) + t) * HDn;
                    #pragma unroll
                    for (int nj = 0; nj < 4; ++nj)
                        Vo[ob + nj * 16 + l15] = f2b(acc[mi][nj][r2]);
                }
        } else {
            ushort_t* dst = i3 ? Ko : Qo;
            // q scale = 1/sqrt(HD) * log2(e)  -> scores in log2 domain
            const float sc = i3 ? 1.0f : 0.18033688f;
            const float inv0 = __powf(10000.0f, -(float)l15 * (1.0f / 32.0f));
            const float inv1 = __powf(10000.0f, -(float)(16 + l15) * (1.0f / 32.0f));
            #pragma unroll
            for (int mi = 0; mi < 4; ++mi)
                #pragma unroll
                for (int r2 = 0; r2 < 4; ++r2) {
                    int m = bm + wr * 64 + mi * 16 + lh * 4 + r2;
                    int b_ = m >> 11, t = m & 2047;
                    size_t ob = ((size_t)((b_ * Hn + hh) * Tn) + t) * HDn;
                    float tf = (float)t;
                    #pragma unroll
                    for (int nj = 0; nj < 2; ++nj) {
                        float fr = tf * (nj ? inv1 : inv0);
                        float cc, ss;
                        __sincosf(fr, &ss, &cc);
                        float v0 = acc[mi][nj][r2], v1 = acc[mi][nj + 2][r2];
                        int j = nj * 16 + l15;
                        dst[ob + j]      = f2b((v0 * cc - v1 * ss) * sc);
                        dst[ob + j + 32] = f2b((v1 * cc + v0 * ss) * sc);
                    }
                }
        }
    } else {
        #pragma unroll
        for (int mi = 0; mi < 4; ++mi)
            #pragma unroll
            for (int nj = 0; nj < 4; ++nj)
                #pragma unroll
                for (int r2 = 0; r2 < 4; ++r2) {
                    int m = bm + wr * 64 + mi * 16 + lh * 4 + r2;
                    int n = bn + wc * 64 + nj * 16 + l15;
                    C[(size_t)m * 1024 + n] = acc[mi][nj][r2];
                }
    }
}
// keep <1> compiled to preserve the module's codegen context (rule #19)
template __global__ void gemm_kernel<1>(
    const ushort_t* __restrict__, const ushort_t* __restrict__,
    ushort_t* __restrict__, ushort_t* __restrict__, ushort_t* __restrict__,
    float* __restrict__, int);

// ---------------------------------------------------------------------------
// Output projection GEMM, BM=64 x BN=128 (R19-proven, unchanged): grid
// (8, 64) = 512 blocks = 2/CU. 4 waves = 1x4 column groups; acc[4][2].
// ---------------------------------------------------------------------------
__global__ __launch_bounds__(256) void gemm_proj64_kernel(
    const ushort_t* __restrict__ A, const ushort_t* __restrict__ Bt,
    float* __restrict__ C)
{
    __shared__ __align__(16) ushort_t As[2][64 * 32];
    __shared__ __align__(16) ushort_t Bs[2][128 * 32];
    const int tid  = threadIdx.x;
    const int lane = tid & 63, wid = tid >> 6;           // wid 0..3 = col group
    const int l15 = lane & 15, lh = lane >> 4;

    const int nbx = gridDim.x;
    const int bid = blockIdx.y * nbx + blockIdx.x;
    const int xcd = bid & 7, r = bid >> 3;
    const int xm = xcd >> 1, xn = xcd & 1;
    const int bmc = gridDim.y >> 2;
    const int bnc = nbx >> 1;
    const int rm = r % bmc, rn = r / bmc;
    const int bm = (xm * bmc + rm) * 64;
    const int bn = (xn * bnc + rn) * 128;

    f32x4 acc[4][2];
    #pragma unroll
    for (int i = 0; i < 4; ++i)
        #pragma unroll
        for (int j = 0; j < 2; ++j) acc[i][j] = (f32x4){0.f, 0.f, 0.f, 0.f};

    const ushort_t* Ag = A  + (size_t)bm * 1024;
    const ushort_t* Bg = Bt + (size_t)bn * 1024;

    auto STAGE = [&](int k0, int buf) {
        {
            int row = tid >> 2, kc = tid & 3;
            int src_k = k0 + ((kc ^ ((row >> 1) & 3)) * 8);
            gload_lds16(Ag + (size_t)row * 1024 + src_k, &As[buf][tid * 8]);
        }
        #pragma unroll
        for (int i = 0; i < 2; ++i) {
            int idx = i * 256 + tid;
            int row = idx >> 2, kc = idx & 3;
            int src_k = k0 + ((kc ^ ((row >> 1) & 3)) * 8);
            gload_lds16(Bg + (size_t)row * 1024 + src_k, &Bs[buf][idx * 8]);
        }
    };

    STAGE(0, 0);
    __syncthreads();

    for (int t = 0; t < 32; ++t) {
        const int cur = t & 1;
        if (t + 1 < 32) STAGE((t + 1) * 32, cur ^ 1);

        short8 a[4], b[2];
        #pragma unroll
        for (int mi = 0; mi < 4; ++mi) {
            int ra = mi * 16 + l15;
            a[mi] = *(const short8*)&As[cur][ra * 32 + ((lh ^ ((ra >> 1) & 3)) * 8)];
        }
        #pragma unroll
        for (int nj = 0; nj < 2; ++nj) {
            int rb = wid * 32 + nj * 16 + l15;
            b[nj] = *(const short8*)&Bs[cur][rb * 32 + ((lh ^ ((rb >> 1) & 3)) * 8)];
        }
        __builtin_amdgcn_s_setprio(1);
        #pragma unroll
        for (int mi = 0; mi < 4; ++mi)
            #pragma unroll
            for (int nj = 0; nj < 2; ++nj)
                acc[mi][nj] = MFMA16(a[mi], b[nj], acc[mi][nj]);
        __builtin_amdgcn_s_setprio(0);

        __syncthreads();
    }

    #pragma unroll
    for (int mi = 0; mi < 4; ++mi)
        #pragma unroll
        for (int nj = 0; nj < 2; ++nj)
            #pragma unroll
            for (int r2 = 0; r2 < 4; ++r2) {
                int m = bm + mi * 16 + lh * 4 + r2;
                int n = bn + wid * 32 + nj * 16 + l15;
                C[(size_t)m * 1024 + n] = acc[mi][nj][r2];
            }
}

// ---------------------------------------------------------------------------
// Flash attention v5.4 (R14/R16/R18-proven, unchanged): one q-tile per
// block, parity-split KV (LDS-staged K via gload_lds — staging IS the
// coalescing mechanism, R17 lesson), single state, single-buffered Vt,
// dbuf K, exp2 softmax + T13 defer-max, max3 tree, shfl cross-half reduce.
// LDS 52KB -> 3 blk/CU. Grid (32 bh fast, 32 slot), qt = 31 - slot (LPT).
// ---------------------------------------------------------------------------
#define ATTN_STEP(PO, MM, LL)                                                   \
  do {                                                                          \
    f32x16 st;                                                                  \
    _Pragma("unroll") for (int k = 0; k < 16; ++k) st[k] = 0.f;                 \
    __builtin_amdgcn_s_setprio(1);                                              \
    {                                                                           \
      const int keyr = h2 * 32 + l31;                                          \
      const ushort_t* kbase = &Ks_c[cur * 4096 + keyr * 64];                    \
      _Pragma("unroll") for (int dk = 0; dk < 4; ++dk) {                        \
        short8 kf = *(const short8*)(kbase + (((dk * 2 + h) ^ (l31 & 7)) * 8)); \
        st = MFMA32(kf, qf[dk], st);                                            \
      }                                                                         \
    }                                                                           \
    __builtin_amdgcn_s_setprio(0);                                              \
    if (kt == qt) {                                                             \
      const int qloc = sub * 32 + l31;                                          \
      _Pragma("unroll") for (int r = 0; r < 16; ++r) {                          \
        int keyloc = h2 * 32 + (r & 3) + 8 * (r >> 2) + 4 * h;                  \
        if (keyloc > qloc) st[r] = -1e30f;                                      \
      }                                                                         \
    }                                                                           \
    float m0 = fmax3(st[0],  st[1],  st[2]);                                    \
    float m1 = fmax3(st[3],  st[4],  st[5]);                                    \
    float m2 = fmax3(st[6],  st[7],  st[8]);                                    \
    float m3 = fmax3(st[9],  st[10], st[11]);                                   \
    float m4 = fmax3(st[12], st[13], st[14]);                                   \
    float n0 = fmax3(m0, m1, m2);                                               \
    float n1 = fmax3(m3, m4, st[15]);                                           \
    float mt = xhalf_max(fmaxf(n0, n1));                                        \
    if (!__all(mt <= MM + 11.0f)) {    /* T13: rescale only on real growth */   \
      float mnew = fmaxf(MM, mt);                                               \
      float cr = fexp2(MM - mnew);                                              \
      MM = mnew;                                                                \
      LL *= cr;                                                                 \
      _Pragma("unroll") for (int db = 0; db < 2; ++db)                          \
        _Pragma("unroll") for (int k = 0; k < 16; ++k) PO[db][k] *= cr;         \
    }                                                                           \
    _Pragma("unroll") for (int k = 0; k < 16; ++k) st[k] = fexp2(st[k] - MM);   \
    float t8[8];                                                                \
    _Pragma("unroll") for (int k = 0; k < 8; ++k) t8[k] = st[k] + st[k + 8];    \
    _Pragma("unroll") for (int stp = 4; stp >= 1; stp >>= 1)                    \
      _Pragma("unroll") for (int k = 0; k < stp; ++k) t8[k] += t8[k + stp];     \
    LL += xhalf_add(t8[0]);                                                     \
    {                                                                           \
      unsigned w0 = cvt_pk(st[0], st[1]);   unsigned w1 = cvt_pk(st[2], st[3]); \
      unsigned w2 = cvt_pk(st[4], st[5]);   unsigned w3 = cvt_pk(st[6], st[7]); \
      unsigned w4 = cvt_pk(st[8], st[9]);   unsigned w5 = cvt_pk(st[10], st[11]); \
      unsigned w6 = cvt_pk(st[12], st[13]); unsigned w7 = cvt_pk(st[14], st[15]); \
      plswap(w0, w2); plswap(w1, w3); plswap(w4, w6); plswap(w5, w7);           \
      union { unsigned u[4]; short8 s8; } f0, f1;                               \
      f0.u[0] = w0; f0.u[1] = w1; f0.u[2] = w2; f0.u[3] = w3;                   \
      f1.u[0] = w4; f1.u[1] = w5; f1.u[2] = w6; f1.u[3] = w7;                   \
      __builtin_amdgcn_s_setprio(1);                                            \
      _Pragma("unroll") for (int db = 0; db < 2; ++db) {                        \
        const int d = db * 32 + l31;                                            \
        const int ck0 = 4 * h2 + h;                                             \
        short8 vf0 = *(const short8*)&Vt_c[d][((ck0 + (d >> 3)) & 7) * 8];      \
        PO[db] = MFMA32(vf0, f0.s8, PO[db]);                                    \
        const int ck1 = 4 * h2 + 2 + h;                                         \
        short8 vf1 = *(const short8*)&Vt_c[d][((ck1 + (d >> 3)) & 7) * 8];      \
        PO[db] = MFMA32(vf1, f1.s8, PO[db]);                                    \
      }                                                                         \
      __builtin_amdgcn_s_setprio(0);                                            \
    }                                                                           \
  } while (0)

__global__ __launch_bounds__(512, 4) void attn_kernel(
    const ushort_t* __restrict__ Q, const ushort_t* __restrict__ K,
    const ushort_t* __restrict__ V, ushort_t* __restrict__ AO)
{
    __shared__ __align__(16) char smem[52224];
    ushort_t* KsE = (ushort_t*)smem;                          // [2][4096]
    ushort_t (*VtE)[72] = (ushort_t(*)[72])(smem + 16384);    // [64][72]
    ushort_t* KsO = (ushort_t*)(smem + 25600);
    ushort_t (*VtO)[72] = (ushort_t(*)[72])(smem + 41984);
    float* carve = (float*)smem;

    const int tid = threadIdx.x;
    const int lane = tid & 63, wid = tid >> 6;
    const int l31 = lane & 31, h = lane >> 5;
    const int bh = blockIdx.x;                // XCD = bh%8 (bh fast)
    const int qt = 31 - blockIdx.y;           // big blocks first (LPT backfill)
    const int sub = wid & 1, h2 = (wid >> 1) & 1, par = wid >> 2;
    const size_t base = (size_t)bh * (Tn * HDn);
    const int nIter = (qt >> 1) + 1;

    const int s = tid >> 8;
    const int ltid = tid & 255;
    ushort_t* Ks_s = s ? KsO : KsE;
    ushort_t (*Vt_s)[72] = s ? VtO : VtE;
    ushort_t* Ks_c = par ? KsO : KsE;
    ushort_t (*Vt_c)[72] = par ? VtO : VtE;
    const int vkp = (ltid >> 3) * 2, vc = ltid & 7;

    short8 qf[4];
    {
        const ushort_t* qp = Q + base + (size_t)(qt * 64 + sub * 32 + l31) * 64 + h * 8;
        #pragma unroll
        for (int dk = 0; dk < 4; ++dk) qf[dk] = *(const short8*)(qp + dk * 16);
    }

    f32x16 po[2];
    #pragma unroll
    for (int db = 0; db < 2; ++db)
        #pragma unroll
        for (int k = 0; k < 16; ++k) po[db][k] = 0.f;
    float m = -INFINITY, l = 0.f;

    u16x8 va, vb;
    {
        const ushort_t* ks = K + base + (size_t)s * 4096;
        #pragma unroll
        for (int i = 0; i < 2; ++i) {
            int idx = i * 256 + ltid, key = idx >> 3, c = idx & 7;
            gload_lds16(ks + key * 64 + ((c ^ (key & 7)) * 8), &Ks_s[idx * 8]);
        }
        const ushort_t* v0 = V + base + (size_t)s * 4096 + (size_t)vkp * 64 + vc * 8;
        va = *(const u16x8*)v0;
        vb = *(const u16x8*)(v0 + 64);
        #pragma unroll
        for (int j = 0; j < 8; ++j) {
            int d = vc * 8 + j;
            unsigned w = (unsigned)va[j] | ((unsigned)vb[j] << 16);
            int blk = ((vkp >> 3) + (d >> 3)) & 7;
            *(unsigned*)&Vt_s[d][blk * 8 + (vkp & 7)] = w;
        }
    }
    __syncthreads();

    for (int i = 0; i < nIter; ++i) {
        const int cur = i & 1;
        const int ktn = 2 * (i + 1) + s;
        const bool doPf = (ktn <= qt);
        if (doPf) {
            const ushort_t* ks = K + base + (size_t)ktn * 4096;
            #pragma unroll
            for (int ii = 0; ii < 2; ++ii) {
                int idx = ii * 256 + ltid, key = idx >> 3, c = idx & 7;
                gload_lds16(ks + key * 64 + ((c ^ (key & 7)) * 8),
                            &Ks_s[(cur ^ 1) * 4096 + idx * 8]);
            }
            const ushort_t* v0 = V + base + (size_t)ktn * 4096 + (size_t)vkp * 64 + vc * 8;
            va = *(const u16x8*)v0;
            vb = *(const u16x8*)(v0 + 64);
        }

        const int kt = 2 * i + par;
        if (kt <= qt && !(kt == qt && h2 > sub)) {
            ATTN_STEP(po, m, l);
        }

        __syncthreads();                          // all waves done reading Vt
        if (doPf) {
            #pragma unroll
            for (int j = 0; j < 8; ++j) {
                int d = vc * 8 + j;
                unsigned w = (unsigned)va[j] | ((unsigned)vb[j] << 16);
                int blk = ((vkp >> 3) + (d >> 3)) & 7;
                *(unsigned*)&Vt_s[d][blk * 8 + (vkp & 7)] = w;
            }
        }
        __syncthreads();                          // Vt(i+1) ready; K loads drained
    }

    // ---- 4-way merge (par x h2) per sub, one round (log2 domain) ----
    const int b_ = bh >> 4, head = bh & 15;
    if (wid >= 2) {
        float* dstp = carve + (size_t)(wid - 2) * 2176 + lane * 34;
        dstp[0] = m; dstp[1] = l;
        #pragma unroll
        for (int db = 0; db < 2; ++db)
            #pragma unroll
            for (int k = 0; k < 16; ++k) dstp[2 + db * 16 + k] = po[db][k];
    }
    __syncthreads();
    if (wid < 2) {
        const float* p0 = carve + (size_t)(wid + 0) * 2176 + lane * 34;
        const float* p1 = carve + (size_t)(wid + 2) * 2176 + lane * 34;
        const float* p2 = carve + (size_t)(wid + 4) * 2176 + lane * 34;
        float m0 = p0[0], l0 = p0[1], m1 = p1[0], l1 = p1[1], m2 = p2[0], l2 = p2[1];
        float mf = fmaxf(fmaxf(m, m0), fmaxf(m1, m2));
        float c  = fexp2(m - mf), c0 = fexp2(m0 - mf);
        float c1 = fexp2(m1 - mf), c2 = fexp2(m2 - mf);
        float lf = l * c + l0 * c0 + l1 * c1 + l2 * c2;
        float inv = 1.0f / lf;
        const int qg2 = qt * 64 + wid * 32 + l31;
        ushort_t* orow = AO + ((size_t)(b_ * Tn + qg2)) * Dn + head * HDn;
        #pragma unroll
        for (int db = 0; db < 2; ++db) {
            #pragma unroll
            for (int rq = 0; rq < 4; ++rq) {
                u16x4 o4;
                #pragma unroll
                for (int rr = 0; rr < 4; ++rr) {
                    int k = rq * 4 + rr;
                    float v = (po[db][k] * c + p0[2 + db * 16 + k] * c0 +
                               p1[2 + db * 16 + k] * c1 + p2[2 + db * 16 + k] * c2) * inv;
                    o4[rr] = f2b(v);
                }
                *(u16x4*)&orow[db * 32 + 8 * rq + 4 * h] = o4;
            }
        }
    }
}

// ---------------------------------------------------------------------------
extern "C" void kernel_launch(void* const* d_in, const int* in_sizes, int n_in,
                              void* d_out, int out_size, void* d_ws, size_t ws_size,
                              hipStream_t stream)
{
    const float* x     = (const float*)d_in[0];
    const float* Wqkv  = (const float*)d_in[1];
    const float* Wproj = (const float*)d_in[2];
    float* out = (float*)d_out;

    ushort_t* ws = (ushort_t*)d_ws;
    ushort_t* xb     = ws;
    ushort_t* Wqkvt  = xb     + 4194304;
    ushort_t* Wprojt = Wqkvt  + 3145728;
    ushort_t* Qb     = Wprojt + 1048576;
    ushort_t* Kb     = Qb     + 4194304;
    ushort_t* Vb     = Kb     + 4194304;
    ushort_t* AOb    = Vb     + 4194304;

    // merged prep: cast + both weight transposes in ONE launch
    prep_kernel<<<2048 + 4096, 256, 0, stream>>>(x, xb, Wqkv, Wqkvt, Wproj, Wprojt);

    // QKV projection with fused RoPE (counted-vmcnt 3-buffer pipeline)
    gemm_kernel<0><<<dim3(3072 / 128, 4096 / 128), 256, 0, stream>>>(
        xb, Wqkvt, Qb, Kb, Vb, nullptr, 3072);

    // flash attention: one q-tile per block, big-first dispatch, bh-major
    attn_kernel<<<dim3(Bn * Hn, 32), 512, 0, stream>>>(Qb, Kb, Vb, AOb);

    // output projection: BM=64 tile -> 512 blocks = 2/CU
    gemm_proj64_kernel<<<dim3(8, 64), 256, 0, stream>>>(AOb, Wprojt, out);
}

// Round 24
// 100.886 us; speedup vs baseline: 1.2010x; 1.0168x over previous
//
#include <hip/hip_runtime.h>
#include <hip/hip_bf16.h>
#include <math.h>

// Problem constants
#define Bn  2
#define Tn  2048
#define Dn  1024
#define Hn  16
#define HDn 64
// M = B*T = 4096

typedef __attribute__((ext_vector_type(8))) short short8;
typedef __attribute__((ext_vector_type(8))) unsigned short u16x8;
typedef __attribute__((ext_vector_type(4))) unsigned short u16x4;
typedef __attribute__((ext_vector_type(4))) float f32x4;
typedef __attribute__((ext_vector_type(16))) float f32x16;
typedef unsigned short ushort_t;

#define MFMA16(a, b, c) __builtin_amdgcn_mfma_f32_16x16x32_bf16((a), (b), (c), 0, 0, 0)
#define MFMA32(a, b, c) __builtin_amdgcn_mfma_f32_32x32x16_bf16((a), (b), (c), 0, 0, 0)

__device__ __forceinline__ unsigned short f2b(float f) {
    union { float f; unsigned u; } v; v.f = f;
    unsigned r = (v.u + 0x7FFFu + ((v.u >> 16) & 1u)) >> 16;   // RNE
    return (unsigned short)r;
}
__device__ __forceinline__ void gload_lds16(const void* g, void* l) {
    __builtin_amdgcn_global_load_lds(
        (const __attribute__((address_space(1))) void*)g,
        (__attribute__((address_space(3))) void*)l, 16, 0, 0);
}
__device__ __forceinline__ unsigned cvt_pk(float lo, float hi) {
    unsigned r;
    asm("v_cvt_pk_bf16_f32 %0, %1, %2" : "=v"(r) : "v"(lo), "v"(hi));
    return r;
}
// permlane32_swap with DISTINCT SSA values only (b==a would coalesce registers).
// Inputs must come from compiler-scheduled code, never from an immediately-
// preceding hand-written asm op (R12 hazard lesson).
__device__ __forceinline__ void plswap(unsigned &a, unsigned &b) {
    asm volatile("v_permlane32_swap_b32 %0, %1" : "+v"(a), "+v"(b));
}
// cross-half (lane ^ 32) reductions via shfl — PROVEN form (R5-R23)
__device__ __forceinline__ float xhalf_max(float v) {
    return fmaxf(v, __shfl_xor(v, 32));
}
__device__ __forceinline__ float xhalf_add(float v) {
    return v + __shfl_xor(v, 32);
}
// bare 2^x (scores live in log2 domain; log2e folded into Q scale)
__device__ __forceinline__ float fexp2(float x) {
    float r;
    asm("v_exp_f32 %0, %1" : "=v"(r) : "v"(x));
    return r;
}
__device__ __forceinline__ float fmax3(float a, float b, float c) {
    float r;
    asm("v_max3_f32 %0, %1, %2, %3" : "=v"(r) : "v"(a), "v"(b), "v"(c));
    return r;
}

// ---------------------------------------------------------------------------
// Merged prep: blocks 0..2047 cast x (f32)->bf16 (vectorized);
// blocks 2048..6143 do both weight transposes (branch is block-uniform,
// so the transpose-path __syncthreads is safe).
// ---------------------------------------------------------------------------
__global__ __launch_bounds__(256) void prep_kernel(
    const float* __restrict__ x, ushort_t* __restrict__ xb,
    const float* __restrict__ Wq, ushort_t* __restrict__ Wqt,
    const float* __restrict__ Wp, ushort_t* __restrict__ Wpt)
{
    __shared__ float tile[32][33];
    const int bid = blockIdx.x;
    if (bid < 2048) {
        int i = bid * 256 + threadIdx.x;
        const float4* p = (const float4*)x;
        float4 a = p[i * 2], b = p[i * 2 + 1];
        u16x8 o;
        o[0] = f2b(a.x); o[1] = f2b(a.y); o[2] = f2b(a.z); o[3] = f2b(a.w);
        o[4] = f2b(b.x); o[5] = f2b(b.y); o[6] = f2b(b.z); o[7] = f2b(b.w);
        *(u16x8*)&xb[i * 8] = o;
        return;
    }
    const int idx = bid - 2048;               // 0..4095
    const int bx = idx & 127, ky = idx >> 7;  // 128 x-blocks, 32 k-blocks
    const float* W;
    ushort_t* Wt;
    int N, n0;
    if (bx < 96) { W = Wq; Wt = Wqt; N = 3072; n0 = bx * 32; }
    else         { W = Wp; Wt = Wpt; N = 1024; n0 = (bx - 96) * 32; }
    const int k0 = ky * 32;
    const int tx = threadIdx.x & 31, ty = threadIdx.x >> 5;
    #pragma unroll
    for (int i = 0; i < 4; ++i)
        tile[ty + i * 8][tx] = W[(size_t)(k0 + ty + i * 8) * N + n0 + tx];
    __syncthreads();
    #pragma unroll
    for (int i = 0; i < 4; ++i)
        Wt[(size_t)(n0 + ty + i * 8) * 1024 + k0 + tx] = f2b(tile[tx][ty + i * 8]);
}

// ---------------------------------------------------------------------------
// bf16 MFMA GEMM — R23 form (proven): T4 counted-vmcnt 3-buffer pipeline,
// row-pair XOR swizzle, 2-D XCD chunking, sincos RoPE epilogue.
// ---------------------------------------------------------------------------
template <int EPI>
__global__ __launch_bounds__(256) void gemm_kernel(
    const ushort_t* __restrict__ A, const ushort_t* __restrict__ Bt,
    ushort_t* __restrict__ Qo, ushort_t* __restrict__ Ko, ushort_t* __restrict__ Vo,
    float* __restrict__ C, int Ncols)
{
    __shared__ __align__(16) ushort_t As[3][128 * 32];
    __shared__ __align__(16) ushort_t Bs[3][128 * 32];
    const int tid  = threadIdx.x;
    const int lane = tid & 63, wid = tid >> 6;
    const int l15 = lane & 15, lh = lane >> 4;
    const int wr = wid >> 1, wc = wid & 1;

    const int nbx = gridDim.x;
    const int bid = blockIdx.y * nbx + blockIdx.x;
    const int xcd = bid & 7, r = bid >> 3;
    const int xm = xcd >> 1, xn = xcd & 1;
    const int bmc = gridDim.y >> 2;
    const int bnc = nbx >> 1;
    const int rm = r % bmc, rn = r / bmc;
    const int bm = (xm * bmc + rm) * 128;
    const int bn = (xn * bnc + rn) * 128;

    f32x4 acc[4][4];
    #pragma unroll
    for (int i = 0; i < 4; ++i)
        #pragma unroll
        for (int j = 0; j < 4; ++j) acc[i][j] = (f32x4){0.f, 0.f, 0.f, 0.f};

    const ushort_t* Ag = A  + (size_t)bm * 1024;
    const ushort_t* Bg = Bt + (size_t)bn * 1024;

    auto STAGE = [&](int k0, int buf) {
        #pragma unroll
        for (int i = 0; i < 2; ++i) {
            int idx = i * 256 + tid;
            int row = idx >> 2, kc = idx & 3;
            int src_k = k0 + ((kc ^ ((row >> 1) & 3)) * 8);   // row-pair XOR
            gload_lds16(Ag + (size_t)row * 1024 + src_k, &As[buf][idx * 8]);
            gload_lds16(Bg + (size_t)row * 1024 + src_k, &Bs[buf][idx * 8]);
        }
    };

    STAGE(0, 0);
    STAGE(32, 1);                 // 8 loads/thread outstanding

    int cur = 0, nx2 = 2;         // cur = t%3, nx2 = (t+2)%3
    for (int t = 0; t < 32; ++t) {
        if (t + 2 < 32) {
            STAGE((t + 2) * 32, nx2);                       // 12 outstanding
            asm volatile("s_waitcnt vmcnt(8)" ::: "memory"); // tile t landed
        } else if (t + 1 < 32) {
            asm volatile("s_waitcnt vmcnt(4)" ::: "memory");
        } else {
            asm volatile("s_waitcnt vmcnt(0)" ::: "memory");
        }
        __builtin_amdgcn_s_barrier();        // all threads' tile-t loads landed
        __builtin_amdgcn_sched_barrier(0);   // no LDS-read hoisting above barrier

        short8 a[4], b[4];
        #pragma unroll
        for (int mi = 0; mi < 4; ++mi) {
            int ra = wr * 64 + mi * 16 + l15;
            a[mi] = *(const short8*)&As[cur][ra * 32 + ((lh ^ ((ra >> 1) & 3)) * 8)];
        }
        #pragma unroll
        for (int nj = 0; nj < 4; ++nj) {
            int rb = wc * 64 + nj * 16 + l15;
            b[nj] = *(const short8*)&Bs[cur][rb * 32 + ((lh ^ ((rb >> 1) & 3)) * 8)];
        }
        __builtin_amdgcn_s_setprio(1);
        #pragma unroll
        for (int mi = 0; mi < 4; ++mi)
            #pragma unroll
            for (int nj = 0; nj < 4; ++nj)
                acc[mi][nj] = MFMA16(a[mi], b[nj], acc[mi][nj]);
        __builtin_amdgcn_s_setprio(0);

        __builtin_amdgcn_sched_barrier(0);
        __builtin_amdgcn_s_barrier();        // reads of buf[cur] done before
                                             // next iter's STAGE overwrites it
        cur = (cur == 2) ? 0 : cur + 1;
        nx2 = (nx2 == 2) ? 0 : nx2 + 1;
    }

    if (EPI == 0) {
        const int n0 = bn + wc * 64;
        const int i3 = n0 >> 10;              // 0=q, 1=k, 2=v
        const int hh = (n0 >> 6) & 15;
        if (i3 == 2) {
            #pragma unroll
            for (int mi = 0; mi < 4; ++mi)
                #pragma unroll
                for (int r2 = 0; r2 < 4; ++r2) {
                    int m = bm + wr * 64 + mi * 16 + lh * 4 + r2;
                    int b_ = m >> 11, t = m & 2047;
                    size_t ob = ((size_t)((b_ * Hn + hh) * Tn) + t) * HDn;
                    #pragma unroll
                    for (int nj = 0; nj < 4; ++nj)
                        Vo[ob + nj * 16 + l15] = f2b(acc[mi][nj][r2]);
                }
        } else {
            ushort_t* dst = i3 ? Ko : Qo;
            // q scale = 1/sqrt(HD) * log2(e)  -> scores in log2 domain
            const float sc = i3 ? 1.0f : 0.18033688f;
            const float inv0 = __powf(10000.0f, -(float)l15 * (1.0f / 32.0f));
            const float inv1 = __powf(10000.0f, -(float)(16 + l15) * (1.0f / 32.0f));
            #pragma unroll
            for (int mi = 0; mi < 4; ++mi)
                #pragma unroll
                for (int r2 = 0; r2 < 4; ++r2) {
                    int m = bm + wr * 64 + mi * 16 + lh * 4 + r2;
                    int b_ = m >> 11, t = m & 2047;
                    size_t ob = ((size_t)((b_ * Hn + hh) * Tn) + t) * HDn;
                    float tf = (float)t;
                    #pragma unroll
                    for (int nj = 0; nj < 2; ++nj) {
                        float fr = tf * (nj ? inv1 : inv0);
                        float cc, ss;
                        __sincosf(fr, &ss, &cc);
                        float v0 = acc[mi][nj][r2], v1 = acc[mi][nj + 2][r2];
                        int j = nj * 16 + l15;
                        dst[ob + j]      = f2b((v0 * cc - v1 * ss) * sc);
                        dst[ob + j + 32] = f2b((v1 * cc + v0 * ss) * sc);
                    }
                }
        }
    } else {
        #pragma unroll
        for (int mi = 0; mi < 4; ++mi)
            #pragma unroll
            for (int nj = 0; nj < 4; ++nj)
                #pragma unroll
                for (int r2 = 0; r2 < 4; ++r2) {
                    int m = bm + wr * 64 + mi * 16 + lh * 4 + r2;
                    int n = bn + wc * 64 + nj * 16 + l15;
                    C[(size_t)m * 1024 + n] = acc[mi][nj][r2];
                }
    }
}
// keep <1> compiled to preserve the module's codegen context (rule #19)
template __global__ void gemm_kernel<1>(
    const ushort_t* __restrict__, const ushort_t* __restrict__,
    ushort_t* __restrict__, ushort_t* __restrict__, ushort_t* __restrict__,
    float* __restrict__, int);

// ---------------------------------------------------------------------------
// Output projection GEMM, BM=64 x BN=128 + R23's T4 counted-vmcnt 3-buffer
// pipeline (3 loads/thread per STAGE -> steady-state vmcnt(6), tail 3/0).
// LDS 36 KB -> 4 blocks/CU. grid (8, 64) = 512 blocks.
// ---------------------------------------------------------------------------
__global__ __launch_bounds__(256) void gemm_proj64_kernel(
    const ushort_t* __restrict__ A, const ushort_t* __restrict__ Bt,
    float* __restrict__ C)
{
    __shared__ __align__(16) ushort_t As[3][64 * 32];    // 4 KB each
    __shared__ __align__(16) ushort_t Bs[3][128 * 32];   // 8 KB each
    const int tid  = threadIdx.x;
    const int lane = tid & 63, wid = tid >> 6;           // wid 0..3 = col group
    const int l15 = lane & 15, lh = lane >> 4;

    const int nbx = gridDim.x;
    const int bid = blockIdx.y * nbx + blockIdx.x;
    const int xcd = bid & 7, r = bid >> 3;
    const int xm = xcd >> 1, xn = xcd & 1;
    const int bmc = gridDim.y >> 2;
    const int bnc = nbx >> 1;
    const int rm = r % bmc, rn = r / bmc;
    const int bm = (xm * bmc + rm) * 64;
    const int bn = (xn * bnc + rn) * 128;

    f32x4 acc[4][2];
    #pragma unroll
    for (int i = 0; i < 4; ++i)
        #pragma unroll
        for (int j = 0; j < 2; ++j) acc[i][j] = (f32x4){0.f, 0.f, 0.f, 0.f};

    const ushort_t* Ag = A  + (size_t)bm * 1024;
    const ushort_t* Bg = Bt + (size_t)bn * 1024;

    // 3 gload_lds per thread per STAGE (1 A + 2 B)
    auto STAGE = [&](int k0, int buf) {
        {
            int row = tid >> 2, kc = tid & 3;
            int src_k = k0 + ((kc ^ ((row >> 1) & 3)) * 8);
            gload_lds16(Ag + (size_t)row * 1024 + src_k, &As[buf][tid * 8]);
        }
        #pragma unroll
        for (int i = 0; i < 2; ++i) {
            int idx = i * 256 + tid;
            int row = idx >> 2, kc = idx & 3;
            int src_k = k0 + ((kc ^ ((row >> 1) & 3)) * 8);
            gload_lds16(Bg + (size_t)row * 1024 + src_k, &Bs[buf][idx * 8]);
        }
    };

    STAGE(0, 0);
    STAGE(32, 1);                 // 6 loads/thread outstanding

    int cur = 0, nx2 = 2;
    for (int t = 0; t < 32; ++t) {
        if (t + 2 < 32) {
            STAGE((t + 2) * 32, nx2);                       // 9 outstanding
            asm volatile("s_waitcnt vmcnt(6)" ::: "memory"); // tile t landed
        } else if (t + 1 < 32) {
            asm volatile("s_waitcnt vmcnt(3)" ::: "memory");
        } else {
            asm volatile("s_waitcnt vmcnt(0)" ::: "memory");
        }
        __builtin_amdgcn_s_barrier();
        __builtin_amdgcn_sched_barrier(0);

        short8 a[4], b[2];
        #pragma unroll
        for (int mi = 0; mi < 4; ++mi) {
            int ra = mi * 16 + l15;
            a[mi] = *(const short8*)&As[cur][ra * 32 + ((lh ^ ((ra >> 1) & 3)) * 8)];
        }
        #pragma unroll
        for (int nj = 0; nj < 2; ++nj) {
            int rb = wid * 32 + nj * 16 + l15;
            b[nj] = *(const short8*)&Bs[cur][rb * 32 + ((lh ^ ((rb >> 1) & 3)) * 8)];
        }
        __builtin_amdgcn_s_setprio(1);
        #pragma unroll
        for (int mi = 0; mi < 4; ++mi)
            #pragma unroll
            for (int nj = 0; nj < 2; ++nj)
                acc[mi][nj] = MFMA16(a[mi], b[nj], acc[mi][nj]);
        __builtin_amdgcn_s_setprio(0);

        __builtin_amdgcn_sched_barrier(0);
        __builtin_amdgcn_s_barrier();
        cur = (cur == 2) ? 0 : cur + 1;
        nx2 = (nx2 == 2) ? 0 : nx2 + 1;
    }

    #pragma unroll
    for (int mi = 0; mi < 4; ++mi)
        #pragma unroll
        for (int nj = 0; nj < 2; ++nj)
            #pragma unroll
            for (int r2 = 0; r2 < 4; ++r2) {
                int m = bm + mi * 16 + lh * 4 + r2;
                int n = bn + wid * 32 + nj * 16 + l15;
                C[(size_t)m * 1024 + n] = acc[mi][nj][r2];
            }
}

// ---------------------------------------------------------------------------
// Flash attention v5.5: v5.4 + T4-style barrier split. Barrier A is a RAW
// s_barrier (no vmcnt drain): the just-issued K(t+1) gload_lds stays in
// flight across it and has the whole Vt-write window to land. Safe because
// every ds_read feeding ATTN_STEP's MFMAs is lgkm-retired before the wave
// reaches the barrier (data dependence), and the Vt write's va/vb use gets
// the compiler's own precise waitcnt. Barrier B stays __syncthreads(): its
// vmcnt(0) drain now covers K(t+1) AFTER a full compute+write phase (~free).
// sched_barrier(0) keeps the write below barrier A (rule #18 hazard class).
// ---------------------------------------------------------------------------
#define ATTN_STEP(PO, MM, LL)                                                   \
  do {                                                                          \
    f32x16 st;                                                                  \
    _Pragma("unroll") for (int k = 0; k < 16; ++k) st[k] = 0.f;                 \
    __builtin_amdgcn_s_setprio(1);                                              \
    {                                                                           \
      const int keyr = h2 * 32 + l31;                                          \
      const ushort_t* kbase = &Ks_c[cur * 4096 + keyr * 64];                    \
      _Pragma("unroll") for (int dk = 0; dk < 4; ++dk) {                        \
        short8 kf = *(const short8*)(kbase + (((dk * 2 + h) ^ (l31 & 7)) * 8)); \
        st = MFMA32(kf, qf[dk], st);                                            \
      }                                                                         \
    }                                                                           \
    __builtin_amdgcn_s_setprio(0);                                              \
    if (kt == qt) {                                                             \
      const int qloc = sub * 32 + l31;                                          \
      _Pragma("unroll") for (int r = 0; r < 16; ++r) {                          \
        int keyloc = h2 * 32 + (r & 3) + 8 * (r >> 2) + 4 * h;                  \
        if (keyloc > qloc) st[r] = -1e30f;                                      \
      }                                                                         \
    }                                                                           \
    float m0 = fmax3(st[0],  st[1],  st[2]);                                    \
    float m1 = fmax3(st[3],  st[4],  st[5]);                                    \
    float m2 = fmax3(st[6],  st[7],  st[8]);                                    \
    float m3 = fmax3(st[9],  st[10], st[11]);                                   \
    float m4 = fmax3(st[12], st[13], st[14]);                                   \
    float n0 = fmax3(m0, m1, m2);                                               \
    float n1 = fmax3(m3, m4, st[15]);                                           \
    float mt = xhalf_max(fmaxf(n0, n1));                                        \
    if (!__all(mt <= MM + 11.0f)) {    /* T13: rescale only on real growth */   \
      float mnew = fmaxf(MM, mt);                                               \
      float cr = fexp2(MM - mnew);                                              \
      MM = mnew;                                                                \
      LL *= cr;                                                                 \
      _Pragma("unroll") for (int db = 0; db < 2; ++db)                          \
        _Pragma("unroll") for (int k = 0; k < 16; ++k) PO[db][k] *= cr;         \
    }                                                                           \
    _Pragma("unroll") for (int k = 0; k < 16; ++k) st[k] = fexp2(st[k] - MM);   \
    float t8[8];                                                                \
    _Pragma("unroll") for (int k = 0; k < 8; ++k) t8[k] = st[k] + st[k + 8];    \
    _Pragma("unroll") for (int stp = 4; stp >= 1; stp >>= 1)                    \
      _Pragma("unroll") for (int k = 0; k < stp; ++k) t8[k] += t8[k + stp];     \
    LL += xhalf_add(t8[0]);                                                     \
    {                                                                           \
      unsigned w0 = cvt_pk(st[0], st[1]);   unsigned w1 = cvt_pk(st[2], st[3]); \
      unsigned w2 = cvt_pk(st[4], st[5]);   unsigned w3 = cvt_pk(st[6], st[7]); \
      unsigned w4 = cvt_pk(st[8], st[9]);   unsigned w5 = cvt_pk(st[10], st[11]); \
      unsigned w6 = cvt_pk(st[12], st[13]); unsigned w7 = cvt_pk(st[14], st[15]); \
      plswap(w0, w2); plswap(w1, w3); plswap(w4, w6); plswap(w5, w7);           \
      union { unsigned u[4]; short8 s8; } f0, f1;                               \
      f0.u[0] = w0; f0.u[1] = w1; f0.u[2] = w2; f0.u[3] = w3;                   \
      f1.u[0] = w4; f1.u[1] = w5; f1.u[2] = w6; f1.u[3] = w7;                   \
      __builtin_amdgcn_s_setprio(1);                                            \
      _Pragma("unroll") for (int db = 0; db < 2; ++db) {                        \
        const int d = db * 32 + l31;                                            \
        const int ck0 = 4 * h2 + h;                                             \
        short8 vf0 = *(const short8*)&Vt_c[d][((ck0 + (d >> 3)) & 7) * 8];      \
        PO[db] = MFMA32(vf0, f0.s8, PO[db]);                                    \
        const int ck1 = 4 * h2 + 2 + h;                                         \
        short8 vf1 = *(const short8*)&Vt_c[d][((ck1 + (d >> 3)) & 7) * 8];      \
        PO[db] = MFMA32(vf1, f1.s8, PO[db]);                                    \
      }                                                                         \
      __builtin_amdgcn_s_setprio(0);                                            \
    }                                                                           \
  } while (0)

__global__ __launch_bounds__(512, 4) void attn_kernel(
    const ushort_t* __restrict__ Q, const ushort_t* __restrict__ K,
    const ushort_t* __restrict__ V, ushort_t* __restrict__ AO)
{
    __shared__ __align__(16) char smem[52224];
    ushort_t* KsE = (ushort_t*)smem;                          // [2][4096]
    ushort_t (*VtE)[72] = (ushort_t(*)[72])(smem + 16384);    // [64][72]
    ushort_t* KsO = (ushort_t*)(smem + 25600);
    ushort_t (*VtO)[72] = (ushort_t(*)[72])(smem + 41984);
    float* carve = (float*)smem;

    const int tid = threadIdx.x;
    const int lane = tid & 63, wid = tid >> 6;
    const int l31 = lane & 31, h = lane >> 5;
    const int bh = blockIdx.x;                // XCD = bh%8 (bh fast)
    const int qt = 31 - blockIdx.y;           // big blocks first (LPT backfill)
    const int sub = wid & 1, h2 = (wid >> 1) & 1, par = wid >> 2;
    const size_t base = (size_t)bh * (Tn * HDn);
    const int nIter = (qt >> 1) + 1;

    const int s = tid >> 8;
    const int ltid = tid & 255;
    ushort_t* Ks_s = s ? KsO : KsE;
    ushort_t (*Vt_s)[72] = s ? VtO : VtE;
    ushort_t* Ks_c = par ? KsO : KsE;
    ushort_t (*Vt_c)[72] = par ? VtO : VtE;
    const int vkp = (ltid >> 3) * 2, vc = ltid & 7;

    short8 qf[4];
    {
        const ushort_t* qp = Q + base + (size_t)(qt * 64 + sub * 32 + l31) * 64 + h * 8;
        #pragma unroll
        for (int dk = 0; dk < 4; ++dk) qf[dk] = *(const short8*)(qp + dk * 16);
    }

    f32x16 po[2];
    #pragma unroll
    for (int db = 0; db < 2; ++db)
        #pragma unroll
        for (int k = 0; k < 16; ++k) po[db][k] = 0.f;
    float m = -INFINITY, l = 0.f;

    u16x8 va, vb;
    {
        const ushort_t* ks = K + base + (size_t)s * 4096;
        #pragma unroll
        for (int i = 0; i < 2; ++i) {
            int idx = i * 256 + ltid, key = idx >> 3, c = idx & 7;
            gload_lds16(ks + key * 64 + ((c ^ (key & 7)) * 8), &Ks_s[idx * 8]);
        }
        const ushort_t* v0 = V + base + (size_t)s * 4096 + (size_t)vkp * 64 + vc * 8;
        va = *(const u16x8*)v0;
        vb = *(const u16x8*)(v0 + 64);
        #pragma unroll
        for (int j = 0; j < 8; ++j) {
            int d = vc * 8 + j;
            unsigned w = (unsigned)va[j] | ((unsigned)vb[j] << 16);
            int blk = ((vkp >> 3) + (d >> 3)) & 7;
            *(unsigned*)&Vt_s[d][blk * 8 + (vkp & 7)] = w;
        }
    }
    __syncthreads();

    for (int i = 0; i < nIter; ++i) {
        const int cur = i & 1;
        const int ktn = 2 * (i + 1) + s;
        const bool doPf = (ktn <= qt);
        if (doPf) {
            // V reg loads first, then K staging: the Vt write's wait for
            // va/vb then leaves the K loads in flight.
            const ushort_t* v0 = V + base + (size_t)ktn * 4096 + (size_t)vkp * 64 + vc * 8;
            va = *(const u16x8*)v0;
            vb = *(const u16x8*)(v0 + 64);
            const ushort_t* ks = K + base + (size_t)ktn * 4096;
            #pragma unroll
            for (int ii = 0; ii < 2; ++ii) {
                int idx = ii * 256 + ltid, key = idx >> 3, c = idx & 7;
                gload_lds16(ks + key * 64 + ((c ^ (key & 7)) * 8),
                            &Ks_s[(cur ^ 1) * 4096 + idx * 8]);
            }
        }

        const int kt = 2 * i + par;
        if (kt <= qt && !(kt == qt && h2 > sub)) {
            ATTN_STEP(po, m, l);
        }

        __builtin_amdgcn_s_barrier();             // raw: Vt reads retired via
        __builtin_amdgcn_sched_barrier(0);        // data deps; K stays in flight
        if (doPf) {
            #pragma unroll
            for (int j = 0; j < 8; ++j) {
                int d = vc * 8 + j;
                unsigned w = (unsigned)va[j] | ((unsigned)vb[j] << 16);
                int blk = ((vkp >> 3) + (d >> 3)) & 7;
                *(unsigned*)&Vt_s[d][blk * 8 + (vkp & 7)] = w;
            }
        }
        __syncthreads();                          // drains K (landed by now) +
                                                  // Vt writes before next read
    }

    // ---- 4-way merge (par x h2) per sub, one round (log2 domain) ----
    const int b_ = bh >> 4, head = bh & 15;
    if (wid >= 2) {
        float* dstp = carve + (size_t)(wid - 2) * 2176 + lane * 34;
        dstp[0] = m; dstp[1] = l;
        #pragma unroll
        for (int db = 0; db < 2; ++db)
            #pragma unroll
            for (int k = 0; k < 16; ++k) dstp[2 + db * 16 + k] = po[db][k];
    }
    __syncthreads();
    if (wid < 2) {
        const float* p0 = carve + (size_t)(wid + 0) * 2176 + lane * 34;
        const float* p1 = carve + (size_t)(wid + 2) * 2176 + lane * 34;
        const float* p2 = carve + (size_t)(wid + 4) * 2176 + lane * 34;
        float m0 = p0[0], l0 = p0[1], m1 = p1[0], l1 = p1[1], m2 = p2[0], l2 = p2[1];
        float mf = fmaxf(fmaxf(m, m0), fmaxf(m1, m2));
        float c  = fexp2(m - mf), c0 = fexp2(m0 - mf);
        float c1 = fexp2(m1 - mf), c2 = fexp2(m2 - mf);
        float lf = l * c + l0 * c0 + l1 * c1 + l2 * c2;
        float inv = 1.0f / lf;
        const int qg2 = qt * 64 + wid * 32 + l31;
        ushort_t* orow = AO + ((size_t)(b_ * Tn + qg2)) * Dn + head * HDn;
        #pragma unroll
        for (int db = 0; db < 2; ++db) {
            #pragma unroll
            for (int rq = 0; rq < 4; ++rq) {
                u16x4 o4;
                #pragma unroll
                for (int rr = 0; rr < 4; ++rr) {
                    int k = rq * 4 + rr;
                    float v = (po[db][k] * c + p0[2 + db * 16 + k] * c0 +
                               p1[2 + db * 16 + k] * c1 + p2[2 + db * 16 + k] * c2) * inv;
                    o4[rr] = f2b(v);
                }
                *(u16x4*)&orow[db * 32 + 8 * rq + 4 * h] = o4;
            }
        }
    }
}

// ---------------------------------------------------------------------------
extern "C" void kernel_launch(void* const* d_in, const int* in_sizes, int n_in,
                              void* d_out, int out_size, void* d_ws, size_t ws_size,
                              hipStream_t stream)
{
    const float* x     = (const float*)d_in[0];
    const float* Wqkv  = (const float*)d_in[1];
    const float* Wproj = (const float*)d_in[2];
    float* out = (float*)d_out;

    ushort_t* ws = (ushort_t*)d_ws;
    ushort_t* xb     = ws;
    ushort_t* Wqkvt  = xb     + 4194304;
    ushort_t* Wprojt = Wqkvt  + 3145728;
    ushort_t* Qb     = Wprojt + 1048576;
    ushort_t* Kb     = Qb     + 4194304;
    ushort_t* Vb     = Kb     + 4194304;
    ushort_t* AOb    = Vb     + 4194304;

    // merged prep: cast + both weight transposes in ONE launch
    prep_kernel<<<2048 + 4096, 256, 0, stream>>>(x, xb, Wqkv, Wqkvt, Wproj, Wprojt);

    // QKV projection with fused RoPE (counted-vmcnt 3-buffer pipeline)
    gemm_kernel<0><<<dim3(3072 / 128, 4096 / 128), 256, 0, stream>>>(
        xb, Wqkvt, Qb, Kb, Vb, nullptr, 3072);

    // flash attention: one q-tile per block, big-first dispatch, bh-major
    attn_kernel<<<dim3(Bn * Hn, 32), 512, 0, stream>>>(Qb, Kb, Vb, AOb);

    // output projection: counted-vmcnt 3-buffer, 512 blocks
    gemm_proj64_kernel<<<dim3(8, 64), 256, 0, stream>>>(AOb, Wprojt, out);
}

// Round 25
// 100.770 us; speedup vs baseline: 1.2024x; 1.0011x over previous
//
#include <hip/hip_runtime.h>
#include <hip/hip_bf16.h>
#include <math.h>

// Problem constants
#define Bn  2
#define Tn  2048
#define Dn  1024
#define Hn  16
#define HDn 64
// M = B*T = 4096

typedef __attribute__((ext_vector_type(8))) short short8;
typedef __attribute__((ext_vector_type(8))) unsigned short u16x8;
typedef __attribute__((ext_vector_type(4))) unsigned short u16x4;
typedef __attribute__((ext_vector_type(4))) float f32x4;
typedef __attribute__((ext_vector_type(16))) float f32x16;
typedef unsigned short ushort_t;

#define MFMA16(a, b, c) __builtin_amdgcn_mfma_f32_16x16x32_bf16((a), (b), (c), 0, 0, 0)
#define MFMA32(a, b, c) __builtin_amdgcn_mfma_f32_32x32x16_bf16((a), (b), (c), 0, 0, 0)

__device__ __forceinline__ unsigned short f2b(float f) {
    union { float f; unsigned u; } v; v.f = f;
    unsigned r = (v.u + 0x7FFFu + ((v.u >> 16) & 1u)) >> 16;   // RNE
    return (unsigned short)r;
}
__device__ __forceinline__ void gload_lds16(const void* g, void* l) {
    __builtin_amdgcn_global_load_lds(
        (const __attribute__((address_space(1))) void*)g,
        (__attribute__((address_space(3))) void*)l, 16, 0, 0);
}
__device__ __forceinline__ unsigned cvt_pk(float lo, float hi) {
    unsigned r;
    asm("v_cvt_pk_bf16_f32 %0, %1, %2" : "=v"(r) : "v"(lo), "v"(hi));
    return r;
}
// permlane32_swap with DISTINCT SSA values only (b==a would coalesce registers).
// Inputs must come from compiler-scheduled code, never from an immediately-
// preceding hand-written asm op (R12 hazard lesson).
__device__ __forceinline__ void plswap(unsigned &a, unsigned &b) {
    asm volatile("v_permlane32_swap_b32 %0, %1" : "+v"(a), "+v"(b));
}
// cross-half (lane ^ 32) reductions via shfl — PROVEN form (R5-R24)
__device__ __forceinline__ float xhalf_max(float v) {
    return fmaxf(v, __shfl_xor(v, 32));
}
__device__ __forceinline__ float xhalf_add(float v) {
    return v + __shfl_xor(v, 32);
}
// bare 2^x (scores live in log2 domain; log2e folded into Q scale)
__device__ __forceinline__ float fexp2(float x) {
    float r;
    asm("v_exp_f32 %0, %1" : "=v"(r) : "v"(x));
    return r;
}
__device__ __forceinline__ float fmax3(float a, float b, float c) {
    float r;
    asm("v_max3_f32 %0, %1, %2, %3" : "=v"(r) : "v"(a), "v"(b), "v"(c));
    return r;
}

// ---------------------------------------------------------------------------
// Merged prep: blocks 0..2047 cast x (f32)->bf16 (vectorized);
// blocks 2048..6143 do both weight transposes (branch is block-uniform,
// so the transpose-path __syncthreads is safe).
// ---------------------------------------------------------------------------
__global__ __launch_bounds__(256) void prep_kernel(
    const float* __restrict__ x, ushort_t* __restrict__ xb,
    const float* __restrict__ Wq, ushort_t* __restrict__ Wqt,
    const float* __restrict__ Wp, ushort_t* __restrict__ Wpt)
{
    __shared__ float tile[32][33];
    const int bid = blockIdx.x;
    if (bid < 2048) {
        int i = bid * 256 + threadIdx.x;
        const float4* p = (const float4*)x;
        float4 a = p[i * 2], b = p[i * 2 + 1];
        u16x8 o;
        o[0] = f2b(a.x); o[1] = f2b(a.y); o[2] = f2b(a.z); o[3] = f2b(a.w);
        o[4] = f2b(b.x); o[5] = f2b(b.y); o[6] = f2b(b.z); o[7] = f2b(b.w);
        *(u16x8*)&xb[i * 8] = o;
        return;
    }
    const int idx = bid - 2048;               // 0..4095
    const int bx = idx & 127, ky = idx >> 7;  // 128 x-blocks, 32 k-blocks
    const float* W;
    ushort_t* Wt;
    int N, n0;
    if (bx < 96) { W = Wq; Wt = Wqt; N = 3072; n0 = bx * 32; }
    else         { W = Wp; Wt = Wpt; N = 1024; n0 = (bx - 96) * 32; }
    const int k0 = ky * 32;
    const int tx = threadIdx.x & 31, ty = threadIdx.x >> 5;
    #pragma unroll
    for (int i = 0; i < 4; ++i)
        tile[ty + i * 8][tx] = W[(size_t)(k0 + ty + i * 8) * N + n0 + tx];
    __syncthreads();
    #pragma unroll
    for (int i = 0; i < 4; ++i)
        Wt[(size_t)(n0 + ty + i * 8) * 1024 + k0 + tx] = f2b(tile[tx][ty + i * 8]);
}

// ---------------------------------------------------------------------------
// bf16 MFMA GEMM — R23 3-buffer counted-vmcnt pipeline, now SINGLE barrier
// per K-step: at iter t, vmcnt(4) (tiles t,t+1 = 8 loads outstanding; waits
// tile t), s_barrier, THEN issue STAGE(t+2). WAR safe: STAGE(t+2) writes
// buf[(t+2)%3] = buf[(t-1)%3], whose iter-(t-1) reads are complete before
// any wave reaches barrier_t (ds_read data delivered to VGPRs before the
// consuming MFMAs, which precede barrier arrival). RAW safe: barrier follows
// every thread's vmcnt(4). sched_barrier(0) pins both sides (rule #18).
// ---------------------------------------------------------------------------
template <int EPI>
__global__ __launch_bounds__(256) void gemm_kernel(
    const ushort_t* __restrict__ A, const ushort_t* __restrict__ Bt,
    ushort_t* __restrict__ Qo, ushort_t* __restrict__ Ko, ushort_t* __restrict__ Vo,
    float* __restrict__ C, int Ncols)
{
    __shared__ __align__(16) ushort_t As[3][128 * 32];
    __shared__ __align__(16) ushort_t Bs[3][128 * 32];
    const int tid  = threadIdx.x;
    const int lane = tid & 63, wid = tid >> 6;
    const int l15 = lane & 15, lh = lane >> 4;
    const int wr = wid >> 1, wc = wid & 1;

    const int nbx = gridDim.x;
    const int bid = blockIdx.y * nbx + blockIdx.x;
    const int xcd = bid & 7, r = bid >> 3;
    const int xm = xcd >> 1, xn = xcd & 1;
    const int bmc = gridDim.y >> 2;
    const int bnc = nbx >> 1;
    const int rm = r % bmc, rn = r / bmc;
    const int bm = (xm * bmc + rm) * 128;
    const int bn = (xn * bnc + rn) * 128;

    f32x4 acc[4][4];
    #pragma unroll
    for (int i = 0; i < 4; ++i)
        #pragma unroll
        for (int j = 0; j < 4; ++j) acc[i][j] = (f32x4){0.f, 0.f, 0.f, 0.f};

    const ushort_t* Ag = A  + (size_t)bm * 1024;
    const ushort_t* Bg = Bt + (size_t)bn * 1024;

    auto STAGE = [&](int k0, int buf) {
        #pragma unroll
        for (int i = 0; i < 2; ++i) {
            int idx = i * 256 + tid;
            int row = idx >> 2, kc = idx & 3;
            int src_k = k0 + ((kc ^ ((row >> 1) & 3)) * 8);   // row-pair XOR
            gload_lds16(Ag + (size_t)row * 1024 + src_k, &As[buf][idx * 8]);
            gload_lds16(Bg + (size_t)row * 1024 + src_k, &Bs[buf][idx * 8]);
        }
    };

    STAGE(0, 0);
    STAGE(32, 1);                 // 8 loads/thread outstanding

    int cur = 0, nx2 = 2;         // cur = t%3, nx2 = (t+2)%3
    for (int t = 0; t < 32; ++t) {
        if (t + 1 < 32) {
            asm volatile("s_waitcnt vmcnt(4)" ::: "memory"); // tile t landed
        } else {
            asm volatile("s_waitcnt vmcnt(0)" ::: "memory");
        }
        __builtin_amdgcn_sched_barrier(0);
        __builtin_amdgcn_s_barrier();        // single barrier: RAW (tile t
                                             // landed block-wide) + WAR
                                             // (iter t-1 reads of nx2 done)
        __builtin_amdgcn_sched_barrier(0);

        if (t + 2 < 32) STAGE((t + 2) * 32, nx2);   // 8 outstanding again

        short8 a[4], b[4];
        #pragma unroll
        for (int mi = 0; mi < 4; ++mi) {
            int ra = wr * 64 + mi * 16 + l15;
            a[mi] = *(const short8*)&As[cur][ra * 32 + ((lh ^ ((ra >> 1) & 3)) * 8)];
        }
        #pragma unroll
        for (int nj = 0; nj < 4; ++nj) {
            int rb = wc * 64 + nj * 16 + l15;
            b[nj] = *(const short8*)&Bs[cur][rb * 32 + ((lh ^ ((rb >> 1) & 3)) * 8)];
        }
        __builtin_amdgcn_s_setprio(1);
        #pragma unroll
        for (int mi = 0; mi < 4; ++mi)
            #pragma unroll
            for (int nj = 0; nj < 4; ++nj)
                acc[mi][nj] = MFMA16(a[mi], b[nj], acc[mi][nj]);
        __builtin_amdgcn_s_setprio(0);

        cur = (cur == 2) ? 0 : cur + 1;
        nx2 = (nx2 == 2) ? 0 : nx2 + 1;
    }

    if (EPI == 0) {
        const int n0 = bn + wc * 64;
        const int i3 = n0 >> 10;              // 0=q, 1=k, 2=v
        const int hh = (n0 >> 6) & 15;
        if (i3 == 2) {
            #pragma unroll
            for (int mi = 0; mi < 4; ++mi)
                #pragma unroll
                for (int r2 = 0; r2 < 4; ++r2) {
                    int m = bm + wr * 64 + mi * 16 + lh * 4 + r2;
                    int b_ = m >> 11, t = m & 2047;
                    size_t ob = ((size_t)((b_ * Hn + hh) * Tn) + t) * HDn;
                    #pragma unroll
                    for (int nj = 0; nj < 4; ++nj)
                        Vo[ob + nj * 16 + l15] = f2b(acc[mi][nj][r2]);
                }
        } else {
            ushort_t* dst = i3 ? Ko : Qo;
            // q scale = 1/sqrt(HD) * log2(e)  -> scores in log2 domain
            const float sc = i3 ? 1.0f : 0.18033688f;
            const float inv0 = __powf(10000.0f, -(float)l15 * (1.0f / 32.0f));
            const float inv1 = __powf(10000.0f, -(float)(16 + l15) * (1.0f / 32.0f));
            #pragma unroll
            for (int mi = 0; mi < 4; ++mi)
                #pragma unroll
                for (int r2 = 0; r2 < 4; ++r2) {
                    int m = bm + wr * 64 + mi * 16 + lh * 4 + r2;
                    int b_ = m >> 11, t = m & 2047;
                    size_t ob = ((size_t)((b_ * Hn + hh) * Tn) + t) * HDn;
                    float tf = (float)t;
                    #pragma unroll
                    for (int nj = 0; nj < 2; ++nj) {
                        float fr = tf * (nj ? inv1 : inv0);
                        float cc, ss;
                        __sincosf(fr, &ss, &cc);
                        float v0 = acc[mi][nj][r2], v1 = acc[mi][nj + 2][r2];
                        int j = nj * 16 + l15;
                        dst[ob + j]      = f2b((v0 * cc - v1 * ss) * sc);
                        dst[ob + j + 32] = f2b((v1 * cc + v0 * ss) * sc);
                    }
                }
        }
    } else {
        #pragma unroll
        for (int mi = 0; mi < 4; ++mi)
            #pragma unroll
            for (int nj = 0; nj < 4; ++nj)
                #pragma unroll
                for (int r2 = 0; r2 < 4; ++r2) {
                    int m = bm + wr * 64 + mi * 16 + lh * 4 + r2;
                    int n = bn + wc * 64 + nj * 16 + l15;
                    C[(size_t)m * 1024 + n] = acc[mi][nj][r2];
                }
    }
}
// keep <1> compiled to preserve the module's codegen context (rule #19)
template __global__ void gemm_kernel<1>(
    const ushort_t* __restrict__, const ushort_t* __restrict__,
    ushort_t* __restrict__, ushort_t* __restrict__, ushort_t* __restrict__,
    float* __restrict__, int);

// ---------------------------------------------------------------------------
// Output projection GEMM, BM=64 x BN=128, 3-buffer counted-vmcnt pipeline
// with the same SINGLE-barrier iteration (vmcnt(3) steady, 0 tail).
// LDS 36 KB. grid (8, 64) = 512 blocks.
// ---------------------------------------------------------------------------
__global__ __launch_bounds__(256) void gemm_proj64_kernel(
    const ushort_t* __restrict__ A, const ushort_t* __restrict__ Bt,
    float* __restrict__ C)
{
    __shared__ __align__(16) ushort_t As[3][64 * 32];    // 4 KB each
    __shared__ __align__(16) ushort_t Bs[3][128 * 32];   // 8 KB each
    const int tid  = threadIdx.x;
    const int lane = tid & 63, wid = tid >> 6;           // wid 0..3 = col group
    const int l15 = lane & 15, lh = lane >> 4;

    const int nbx = gridDim.x;
    const int bid = blockIdx.y * nbx + blockIdx.x;
    const int xcd = bid & 7, r = bid >> 3;
    const int xm = xcd >> 1, xn = xcd & 1;
    const int bmc = gridDim.y >> 2;
    const int bnc = nbx >> 1;
    const int rm = r % bmc, rn = r / bmc;
    const int bm = (xm * bmc + rm) * 64;
    const int bn = (xn * bnc + rn) * 128;

    f32x4 acc[4][2];
    #pragma unroll
    for (int i = 0; i < 4; ++i)
        #pragma unroll
        for (int j = 0; j < 2; ++j) acc[i][j] = (f32x4){0.f, 0.f, 0.f, 0.f};

    const ushort_t* Ag = A  + (size_t)bm * 1024;
    const ushort_t* Bg = Bt + (size_t)bn * 1024;

    // 3 gload_lds per thread per STAGE (1 A + 2 B)
    auto STAGE = [&](int k0, int buf) {
        {
            int row = tid >> 2, kc = tid & 3;
            int src_k = k0 + ((kc ^ ((row >> 1) & 3)) * 8);
            gload_lds16(Ag + (size_t)row * 1024 + src_k, &As[buf][tid * 8]);
        }
        #pragma unroll
        for (int i = 0; i < 2; ++i) {
            int idx = i * 256 + tid;
            int row = idx >> 2, kc = idx & 3;
            int src_k = k0 + ((kc ^ ((row >> 1) & 3)) * 8);
            gload_lds16(Bg + (size_t)row * 1024 + src_k, &Bs[buf][idx * 8]);
        }
    };

    STAGE(0, 0);
    STAGE(32, 1);                 // 6 loads/thread outstanding

    int cur = 0, nx2 = 2;
    for (int t = 0; t < 32; ++t) {
        if (t + 1 < 32) {
            asm volatile("s_waitcnt vmcnt(3)" ::: "memory"); // tile t landed
        } else {
            asm volatile("s_waitcnt vmcnt(0)" ::: "memory");
        }
        __builtin_amdgcn_sched_barrier(0);
        __builtin_amdgcn_s_barrier();
        __builtin_amdgcn_sched_barrier(0);

        if (t + 2 < 32) STAGE((t + 2) * 32, nx2);

        short8 a[4], b[2];
        #pragma unroll
        for (int mi = 0; mi < 4; ++mi) {
            int ra = mi * 16 + l15;
            a[mi] = *(const short8*)&As[cur][ra * 32 + ((lh ^ ((ra >> 1) & 3)) * 8)];
        }
        #pragma unroll
        for (int nj = 0; nj < 2; ++nj) {
            int rb = wid * 32 + nj * 16 + l15;
            b[nj] = *(const short8*)&Bs[cur][rb * 32 + ((lh ^ ((rb >> 1) & 3)) * 8)];
        }
        __builtin_amdgcn_s_setprio(1);
        #pragma unroll
        for (int mi = 0; mi < 4; ++mi)
            #pragma unroll
            for (int nj = 0; nj < 2; ++nj)
                acc[mi][nj] = MFMA16(a[mi], b[nj], acc[mi][nj]);
        __builtin_amdgcn_s_setprio(0);

        cur = (cur == 2) ? 0 : cur + 1;
        nx2 = (nx2 == 2) ? 0 : nx2 + 1;
    }

    #pragma unroll
    for (int mi = 0; mi < 4; ++mi)
        #pragma unroll
        for (int nj = 0; nj < 2; ++nj)
            #pragma unroll
            for (int r2 = 0; r2 < 4; ++r2) {
                int m = bm + mi * 16 + lh * 4 + r2;
                int n = bn + wid * 32 + nj * 16 + l15;
                C[(size_t)m * 1024 + n] = acc[mi][nj][r2];
            }
}

// ---------------------------------------------------------------------------
// Flash attention v5.5 (R24-proven, unchanged): T4 barrier split — raw
// s_barrier A (K loads stay in flight), __syncthreads B (drain after a full
// compute+write window). One q-tile/block, parity-split KV, exp2 softmax +
// T13 defer-max, max3 tree. LDS 52KB -> 3 blk/CU. Grid (32 bh, 32 slot).
// ---------------------------------------------------------------------------
#define ATTN_STEP(PO, MM, LL)                                                   \
  do {                                                                          \
    f32x16 st;                                                                  \
    _Pragma("unroll") for (int k = 0; k < 16; ++k) st[k] = 0.f;                 \
    __builtin_amdgcn_s_setprio(1);                                              \
    {                                                                           \
      const int keyr = h2 * 32 + l31;                                          \
      const ushort_t* kbase = &Ks_c[cur * 4096 + keyr * 64];                    \
      _Pragma("unroll") for (int dk = 0; dk < 4; ++dk) {                        \
        short8 kf = *(const short8*)(kbase + (((dk * 2 + h) ^ (l31 & 7)) * 8)); \
        st = MFMA32(kf, qf[dk], st);                                            \
      }                                                                         \
    }                                                                           \
    __builtin_amdgcn_s_setprio(0);                                              \
    if (kt == qt) {                                                             \
      const int qloc = sub * 32 + l31;                                          \
      _Pragma("unroll") for (int r = 0; r < 16; ++r) {                          \
        int keyloc = h2 * 32 + (r & 3) + 8 * (r >> 2) + 4 * h;                  \
        if (keyloc > qloc) st[r] = -1e30f;                                      \
      }                                                                         \
    }                                                                           \
    float m0 = fmax3(st[0],  st[1],  st[2]);                                    \
    float m1 = fmax3(st[3],  st[4],  st[5]);                                    \
    float m2 = fmax3(st[6],  st[7],  st[8]);                                    \
    float m3 = fmax3(st[9],  st[10], st[11]);                                   \
    float m4 = fmax3(st[12], st[13], st[14]);                                   \
    float n0 = fmax3(m0, m1, m2);                                               \
    float n1 = fmax3(m3, m4, st[15]);                                           \
    float mt = xhalf_max(fmaxf(n0, n1));                                        \
    if (!__all(mt <= MM + 11.0f)) {    /* T13: rescale only on real growth */   \
      float mnew = fmaxf(MM, mt);                                               \
      float cr = fexp2(MM - mnew);                                              \
      MM = mnew;                                                                \
      LL *= cr;                                                                 \
      _Pragma("unroll") for (int db = 0; db < 2; ++db)                          \
        _Pragma("unroll") for (int k = 0; k < 16; ++k) PO[db][k] *= cr;         \
    }                                                                           \
    _Pragma("unroll") for (int k = 0; k < 16; ++k) st[k] = fexp2(st[k] - MM);   \
    float t8[8];                                                                \
    _Pragma("unroll") for (int k = 0; k < 8; ++k) t8[k] = st[k] + st[k + 8];    \
    _Pragma("unroll") for (int stp = 4; stp >= 1; stp >>= 1)                    \
      _Pragma("unroll") for (int k = 0; k < stp; ++k) t8[k] += t8[k + stp];     \
    LL += xhalf_add(t8[0]);                                                     \
    {                                                                           \
      unsigned w0 = cvt_pk(st[0], st[1]);   unsigned w1 = cvt_pk(st[2], st[3]); \
      unsigned w2 = cvt_pk(st[4], st[5]);   unsigned w3 = cvt_pk(st[6], st[7]); \
      unsigned w4 = cvt_pk(st[8], st[9]);   unsigned w5 = cvt_pk(st[10], st[11]); \
      unsigned w6 = cvt_pk(st[12], st[13]); unsigned w7 = cvt_pk(st[14], st[15]); \
      plswap(w0, w2); plswap(w1, w3); plswap(w4, w6); plswap(w5, w7);           \
      union { unsigned u[4]; short8 s8; } f0, f1;                               \
      f0.u[0] = w0; f0.u[1] = w1; f0.u[2] = w2; f0.u[3] = w3;                   \
      f1.u[0] = w4; f1.u[1] = w5; f1.u[2] = w6; f1.u[3] = w7;                   \
      __builtin_amdgcn_s_setprio(1);                                            \
      _Pragma("unroll") for (int db = 0; db < 2; ++db) {                        \
        const int d = db * 32 + l31;                                            \
        const int ck0 = 4 * h2 + h;                                             \
        short8 vf0 = *(const short8*)&Vt_c[d][((ck0 + (d >> 3)) & 7) * 8];      \
        PO[db] = MFMA32(vf0, f0.s8, PO[db]);                                    \
        const int ck1 = 4 * h2 + 2 + h;                                         \
        short8 vf1 = *(const short8*)&Vt_c[d][((ck1 + (d >> 3)) & 7) * 8];      \
        PO[db] = MFMA32(vf1, f1.s8, PO[db]);                                    \
      }                                                                         \
      __builtin_amdgcn_s_setprio(0);                                            \
    }                                                                           \
  } while (0)

__global__ __launch_bounds__(512, 4) void attn_kernel(
    const ushort_t* __restrict__ Q, const ushort_t* __restrict__ K,
    const ushort_t* __restrict__ V, ushort_t* __restrict__ AO)
{
    __shared__ __align__(16) char smem[52224];
    ushort_t* KsE = (ushort_t*)smem;                          // [2][4096]
    ushort_t (*VtE)[72] = (ushort_t(*)[72])(smem + 16384);    // [64][72]
    ushort_t* KsO = (ushort_t*)(smem + 25600);
    ushort_t (*VtO)[72] = (ushort_t(*)[72])(smem + 41984);
    float* carve = (float*)smem;

    const int tid = threadIdx.x;
    const int lane = tid & 63, wid = tid >> 6;
    const int l31 = lane & 31, h = lane >> 5;
    const int bh = blockIdx.x;                // XCD = bh%8 (bh fast)
    const int qt = 31 - blockIdx.y;           // big blocks first (LPT backfill)
    const int sub = wid & 1, h2 = (wid >> 1) & 1, par = wid >> 2;
    const size_t base = (size_t)bh * (Tn * HDn);
    const int nIter = (qt >> 1) + 1;

    const int s = tid >> 8;
    const int ltid = tid & 255;
    ushort_t* Ks_s = s ? KsO : KsE;
    ushort_t (*Vt_s)[72] = s ? VtO : VtE;
    ushort_t* Ks_c = par ? KsO : KsE;
    ushort_t (*Vt_c)[72] = par ? VtO : VtE;
    const int vkp = (ltid >> 3) * 2, vc = ltid & 7;

    short8 qf[4];
    {
        const ushort_t* qp = Q + base + (size_t)(qt * 64 + sub * 32 + l31) * 64 + h * 8;
        #pragma unroll
        for (int dk = 0; dk < 4; ++dk) qf[dk] = *(const short8*)(qp + dk * 16);
    }

    f32x16 po[2];
    #pragma unroll
    for (int db = 0; db < 2; ++db)
        #pragma unroll
        for (int k = 0; k < 16; ++k) po[db][k] = 0.f;
    float m = -INFINITY, l = 0.f;

    u16x8 va, vb;
    {
        const ushort_t* ks = K + base + (size_t)s * 4096;
        #pragma unroll
        for (int i = 0; i < 2; ++i) {
            int idx = i * 256 + ltid, key = idx >> 3, c = idx & 7;
            gload_lds16(ks + key * 64 + ((c ^ (key & 7)) * 8), &Ks_s[idx * 8]);
        }
        const ushort_t* v0 = V + base + (size_t)s * 4096 + (size_t)vkp * 64 + vc * 8;
        va = *(const u16x8*)v0;
        vb = *(const u16x8*)(v0 + 64);
        #pragma unroll
        for (int j = 0; j < 8; ++j) {
            int d = vc * 8 + j;
            unsigned w = (unsigned)va[j] | ((unsigned)vb[j] << 16);
            int blk = ((vkp >> 3) + (d >> 3)) & 7;
            *(unsigned*)&Vt_s[d][blk * 8 + (vkp & 7)] = w;
        }
    }
    __syncthreads();

    for (int i = 0; i < nIter; ++i) {
        const int cur = i & 1;
        const int ktn = 2 * (i + 1) + s;
        const bool doPf = (ktn <= qt);
        if (doPf) {
            // V reg loads first, then K staging: the Vt write's wait for
            // va/vb then leaves the K loads in flight.
            const ushort_t* v0 = V + base + (size_t)ktn * 4096 + (size_t)vkp * 64 + vc * 8;
            va = *(const u16x8*)v0;
            vb = *(const u16x8*)(v0 + 64);
            const ushort_t* ks = K + base + (size_t)ktn * 4096;
            #pragma unroll
            for (int ii = 0; ii < 2; ++ii) {
                int idx = ii * 256 + ltid, key = idx >> 3, c = idx & 7;
                gload_lds16(ks + key * 64 + ((c ^ (key & 7)) * 8),
                            &Ks_s[(cur ^ 1) * 4096 + idx * 8]);
            }
        }

        const int kt = 2 * i + par;
        if (kt <= qt && !(kt == qt && h2 > sub)) {
            ATTN_STEP(po, m, l);
        }

        __builtin_amdgcn_s_barrier();             // raw: Vt reads retired via
        __builtin_amdgcn_sched_barrier(0);        // data deps; K stays in flight
        if (doPf) {
            #pragma unroll
            for (int j = 0; j < 8; ++j) {
                int d = vc * 8 + j;
                unsigned w = (unsigned)va[j] | ((unsigned)vb[j] << 16);
                int blk = ((vkp >> 3) + (d >> 3)) & 7;
                *(unsigned*)&Vt_s[d][blk * 8 + (vkp & 7)] = w;
            }
        }
        __syncthreads();                          // drains K (landed by now) +
                                                  // Vt writes before next read
    }

    // ---- 4-way merge (par x h2) per sub, one round (log2 domain) ----
    const int b_ = bh >> 4, head = bh & 15;
    if (wid >= 2) {
        float* dstp = carve + (size_t)(wid - 2) * 2176 + lane * 34;
        dstp[0] = m; dstp[1] = l;
        #pragma unroll
        for (int db = 0; db < 2; ++db)
            #pragma unroll
            for (int k = 0; k < 16; ++k) dstp[2 + db * 16 + k] = po[db][k];
    }
    __syncthreads();
    if (wid < 2) {
        const float* p0 = carve + (size_t)(wid + 0) * 2176 + lane * 34;
        const float* p1 = carve + (size_t)(wid + 2) * 2176 + lane * 34;
        const float* p2 = carve + (size_t)(wid + 4) * 2176 + lane * 34;
        float m0 = p0[0], l0 = p0[1], m1 = p1[0], l1 = p1[1], m2 = p2[0], l2 = p2[1];
        float mf = fmaxf(fmaxf(m, m0), fmaxf(m1, m2));
        float c  = fexp2(m - mf), c0 = fexp2(m0 - mf);
        float c1 = fexp2(m1 - mf), c2 = fexp2(m2 - mf);
        float lf = l * c + l0 * c0 + l1 * c1 + l2 * c2;
        float inv = 1.0f / lf;
        const int qg2 = qt * 64 + wid * 32 + l31;
        ushort_t* orow = AO + ((size_t)(b_ * Tn + qg2)) * Dn + head * HDn;
        #pragma unroll
        for (int db = 0; db < 2; ++db) {
            #pragma unroll
            for (int rq = 0; rq < 4; ++rq) {
                u16x4 o4;
                #pragma unroll
                for (int rr = 0; rr < 4; ++rr) {
                    int k = rq * 4 + rr;
                    float v = (po[db][k] * c + p0[2 + db * 16 + k] * c0 +
                               p1[2 + db * 16 + k] * c1 + p2[2 + db * 16 + k] * c2) * inv;
                    o4[rr] = f2b(v);
                }
                *(u16x4*)&orow[db * 32 + 8 * rq + 4 * h] = o4;
            }
        }
    }
}

// ---------------------------------------------------------------------------
extern "C" void kernel_launch(void* const* d_in, const int* in_sizes, int n_in,
                              void* d_out, int out_size, void* d_ws, size_t ws_size,
                              hipStream_t stream)
{
    const float* x     = (const float*)d_in[0];
    const float* Wqkv  = (const float*)d_in[1];
    const float* Wproj = (const float*)d_in[2];
    float* out = (float*)d_out;

    ushort_t* ws = (ushort_t*)d_ws;
    ushort_t* xb     = ws;
    ushort_t* Wqkvt  = xb     + 4194304;
    ushort_t* Wprojt = Wqkvt  + 3145728;
    ushort_t* Qb     = Wprojt + 1048576;
    ushort_t* Kb     = Qb     + 4194304;
    ushort_t* Vb     = Kb     + 4194304;
    ushort_t* AOb    = Vb     + 4194304;

    // merged prep: cast + both weight transposes in ONE launch
    prep_kernel<<<2048 + 4096, 256, 0, stream>>>(x, xb, Wqkv, Wqkvt, Wproj, Wprojt);

    // QKV projection with fused RoPE (single-barrier counted-vmcnt pipeline)
    gemm_kernel<0><<<dim3(3072 / 128, 4096 / 128), 256, 0, stream>>>(
        xb, Wqkvt, Qb, Kb, Vb, nullptr, 3072);

    // flash attention: one q-tile per block, big-first dispatch, bh-major
    attn_kernel<<<dim3(Bn * Hn, 32), 512, 0, stream>>>(Qb, Kb, Vb, AOb);

    // output projection: single-barrier counted-vmcnt, 512 blocks
    gemm_proj64_kernel<<<dim3(8, 64), 256, 0, stream>>>(AOb, Wprojt, out);
}